// Round 1
// baseline (7027.612 us; speedup 1.0000x reference)
//
#include <hip/hip_runtime.h>
#include <hip/hip_bf16.h>

#define NN 100000
#define NE 1600000
// IN_CH=500, HID=128, OUT_CH=40

// ---------------- graph norm ----------------
__global__ __launch_bounds__(256) void k_degree(const int* __restrict__ ei,
                                                const float* __restrict__ ea,
                                                float* __restrict__ deg) {
    int e = blockIdx.x * 256 + threadIdx.x;
    if (e < NE) {
        int d = ei[NE + e];
        unsafeAtomicAdd(&deg[d], ea[e]);
    }
}

__global__ __launch_bounds__(256) void k_dinv(const float* __restrict__ deg,
                                              float* __restrict__ dinv) {
    int i = blockIdx.x * 256 + threadIdx.x;
    if (i < NN) {
        float d = deg[i] + 1.0f;  // + self-loop weight 1
        dinv[i] = rsqrtf(d);      // d >= 1 always
    }
}

__global__ __launch_bounds__(256) void k_norm(const int* __restrict__ ei,
                                              const float* __restrict__ ea,
                                              const float* __restrict__ dinv,
                                              float* __restrict__ nrm) {
    int e = blockIdx.x * 256 + threadIdx.x;
    if (e < NE) {
        int s = ei[e];
        int d = ei[NE + e];
        nrm[e] = dinv[s] * ea[e] * dinv[d];
    }
}

// ---------------- fp32 GEMM, N=128 ----------------
// Block: 256 threads -> 32 rows x 128 cols. Each thread: 16 rows, 1 col.
template <int K, int KT>
__global__ __launch_bounds__(256) void k_gemm128(const float* __restrict__ X,
                                                 const float* __restrict__ W,
                                                 float* __restrict__ Out) {
    __shared__ float xs[KT][32];
    const int tid = threadIdx.x;
    const int col = tid & 127;
    const int rbase = (tid >> 7) * 16;
    const int row0 = blockIdx.x * 32;

    float acc[16];
#pragma unroll
    for (int i = 0; i < 16; i++) acc[i] = 0.f;

    for (int kt = 0; kt < K; kt += KT) {
        __syncthreads();
        for (int idx = tid; idx < KT * 32; idx += 256) {
            int r = idx & 31;
            int k = idx >> 5;
            xs[k][r] = X[(size_t)(row0 + r) * K + kt + k];
        }
        __syncthreads();
#pragma unroll 2
        for (int k = 0; k < KT; k++) {
            float w = W[(size_t)(kt + k) * 128 + col];
            const float* xr = &xs[k][rbase];
#pragma unroll
            for (int i = 0; i < 16; i++) acc[i] = fmaf(xr[i], w, acc[i]);
        }
    }
#pragma unroll
    for (int i = 0; i < 16; i++)
        Out[(size_t)(row0 + rbase + i) * 128 + col] = acc[i];
}

// ---------------- fp32 GEMM, K=128, N=40 ----------------
// Block: 256 threads -> 32 rows x 64 col-slots (40 active). 8 rows/thread.
__global__ __launch_bounds__(256) void k_gemm40(const float* __restrict__ X,
                                                const float* __restrict__ W,
                                                float* __restrict__ Out) {
    __shared__ float xs[128][32];
    const int tid = threadIdx.x;
    const int col = tid & 63;
    const int rbase = (tid >> 6) * 8;
    const int row0 = blockIdx.x * 32;

    for (int idx = tid; idx < 128 * 32; idx += 256) {
        int r = idx & 31;
        int k = idx >> 5;
        xs[k][r] = X[(size_t)(row0 + r) * 128 + k];
    }
    __syncthreads();

    float acc[8];
#pragma unroll
    for (int i = 0; i < 8; i++) acc[i] = 0.f;

#pragma unroll 2
    for (int k = 0; k < 128; k++) {
        float w = (col < 40) ? W[k * 40 + col] : 0.f;
        const float* xr = &xs[k][rbase];
#pragma unroll
        for (int i = 0; i < 8; i++) acc[i] = fmaf(xr[i], w, acc[i]);
    }
    if (col < 40) {
#pragma unroll
        for (int i = 0; i < 8; i++)
            Out[(size_t)(row0 + rbase + i) * 40 + col] = acc[i];
    }
}

// ---------------- aggregation ----------------
// Self-loop term initializes the accumulator (no zeroing pass needed).
template <int C>
__global__ __launch_bounds__(256) void k_agg_init(const float* __restrict__ H,
                                                  const float* __restrict__ dinv,
                                                  float* __restrict__ A) {
    const int CG = C / 4;
    int gid = blockIdx.x * 256 + threadIdx.x;
    if (gid >= NN * CG) return;
    int node = gid / CG;
    float dv = dinv[node];
    float s = dv * dv;
    float4 h = reinterpret_cast<const float4*>(H)[gid];
    float4 o;
    o.x = h.x * s; o.y = h.y * s; o.z = h.z * s; o.w = h.w * s;
    reinterpret_cast<float4*>(A)[gid] = o;
}

template <int C>
__global__ __launch_bounds__(256) void k_agg_push(const float* __restrict__ H,
                                                  const int* __restrict__ ei,
                                                  const float* __restrict__ nrm,
                                                  float* __restrict__ A) {
    const int CG = C / 4;
    int gid = blockIdx.x * 256 + threadIdx.x;
    if (gid >= NE * CG) return;
    int e = gid / CG;
    int cg = gid % CG;
    int s = ei[e];
    int d = ei[NE + e];
    float n = nrm[e];
    float4 h = reinterpret_cast<const float4*>(H + (size_t)s * C)[cg];
    float* out = A + (size_t)d * C + cg * 4;
    unsafeAtomicAdd(out + 0, n * h.x);
    unsafeAtomicAdd(out + 1, n * h.y);
    unsafeAtomicAdd(out + 2, n * h.z);
    unsafeAtomicAdd(out + 3, n * h.w);
}

// ---------------- epilogues ----------------
__global__ __launch_bounds__(256) void k_bias_relu(const float* __restrict__ A,
                                                   const float* __restrict__ b,
                                                   float* __restrict__ Hout) {
    int gid = blockIdx.x * 256 + threadIdx.x;  // over NN*32 float4s
    if (gid >= NN * 32) return;
    int cg = gid & 31;
    float4 a = reinterpret_cast<const float4*>(A)[gid];
    float4 bb = reinterpret_cast<const float4*>(b)[cg];
    float4 o;
    o.x = fmaxf(a.x + bb.x, 0.f);
    o.y = fmaxf(a.y + bb.y, 0.f);
    o.z = fmaxf(a.z + bb.z, 0.f);
    o.w = fmaxf(a.w + bb.w, 0.f);
    reinterpret_cast<float4*>(Hout)[gid] = o;
}

__global__ __launch_bounds__(256) void k_bias_relu_res(const float* __restrict__ A,
                                                       const float* __restrict__ b,
                                                       const float* __restrict__ R,
                                                       float* __restrict__ Hout) {
    int gid = blockIdx.x * 256 + threadIdx.x;
    if (gid >= NN * 32) return;
    int cg = gid & 31;
    float4 a = reinterpret_cast<const float4*>(A)[gid];
    float4 bb = reinterpret_cast<const float4*>(b)[cg];
    float4 r = reinterpret_cast<const float4*>(R)[gid];
    float4 o;
    o.x = fmaxf(a.x + bb.x, 0.f) + r.x;
    o.y = fmaxf(a.y + bb.y, 0.f) + r.y;
    o.z = fmaxf(a.z + bb.z, 0.f) + r.z;
    o.w = fmaxf(a.w + bb.w, 0.f) + r.w;
    reinterpret_cast<float4*>(Hout)[gid] = o;
}

// one wave per row (40 active lanes)
__global__ __launch_bounds__(256) void k_logsoftmax(const float* __restrict__ A,
                                                    const float* __restrict__ b,
                                                    float* __restrict__ out) {
    int row = blockIdx.x * 4 + (threadIdx.x >> 6);
    if (row >= NN) return;
    int lane = threadIdx.x & 63;
    float v = -1e30f;
    if (lane < 40) v = A[(size_t)row * 40 + lane] + b[lane];
    float m = v;
    for (int o = 32; o; o >>= 1) m = fmaxf(m, __shfl_xor(m, o));
    float e = (lane < 40) ? expf(v - m) : 0.f;
    float ssum = e;
    for (int o = 32; o; o >>= 1) ssum += __shfl_xor(ssum, o);
    float ls = logf(ssum);
    if (lane < 40) out[(size_t)row * 40 + lane] = v - m - ls;
}

// ---------------- launch ----------------
extern "C" void kernel_launch(void* const* d_in, const int* in_sizes, int n_in,
                              void* d_out, int out_size, void* d_ws, size_t ws_size,
                              hipStream_t stream) {
    const float* x  = (const float*)d_in[0];
    const int*   ei = (const int*)d_in[1];   // [2, NE] int32
    const float* ea = (const float*)d_in[2];
    const float* W1 = (const float*)d_in[3];
    const float* b1 = (const float*)d_in[4];
    const float* W2 = (const float*)d_in[5];
    const float* b2 = (const float*)d_in[6];
    const float* W3 = (const float*)d_in[7];
    const float* b3 = (const float*)d_in[8];
    float* out = (float*)d_out;

    float* ws   = (float*)d_ws;
    float* deg  = ws;                          // NN
    float* dinv = deg + NN;                    // NN
    float* nrm  = dinv + NN;                   // NE
    float* H    = nrm + NE;                    // NN*128 (lin out / h2)
    float* AGG  = H + (size_t)NN * 128;        // NN*128 (agg accum / L3 lin)
    float* h1   = AGG + (size_t)NN * 128;      // NN*128 (relu1 out / agg3)

    hipMemsetAsync(deg, 0, NN * sizeof(float), stream);
    k_degree<<<(NE + 255) / 256, 256, 0, stream>>>(ei, ea, deg);
    k_dinv<<<(NN + 255) / 256, 256, 0, stream>>>(deg, dinv);
    k_norm<<<(NE + 255) / 256, 256, 0, stream>>>(ei, ea, dinv, nrm);

    // ---- layer 1: H = X @ W1 ; AGG ; h1 = relu(AGG + b1)
    k_gemm128<500, 50><<<NN / 32, 256, 0, stream>>>(x, W1, H);
    k_agg_init<128><<<(NN * 32 + 255) / 256, 256, 0, stream>>>(H, dinv, AGG);
    k_agg_push<128><<<(NE * 32 + 255) / 256, 256, 0, stream>>>(H, ei, nrm, AGG);
    k_bias_relu<<<(NN * 32 + 255) / 256, 256, 0, stream>>>(AGG, b1, h1);

    // ---- layer 2: H = h1 @ W2 ; AGG ; H(h2) = relu(AGG + b2) + h1
    k_gemm128<128, 64><<<NN / 32, 256, 0, stream>>>(h1, W2, H);
    k_agg_init<128><<<(NN * 32 + 255) / 256, 256, 0, stream>>>(H, dinv, AGG);
    k_agg_push<128><<<(NE * 32 + 255) / 256, 256, 0, stream>>>(H, ei, nrm, AGG);
    k_bias_relu_res<<<(NN * 32 + 255) / 256, 256, 0, stream>>>(AGG, b2, h1, H);

    // ---- layer 3: AGG(first NN*40) = H(h2) @ W3 ; h1(first NN*40) = agg3
    k_gemm40<<<NN / 32, 256, 0, stream>>>(H, W3, AGG);
    k_agg_init<40><<<(NN * 10 + 255) / 256, 256, 0, stream>>>(AGG, dinv, h1);
    k_agg_push<40><<<(NE * 10 + 255) / 256, 256, 0, stream>>>(AGG, ei, nrm, h1);

    k_logsoftmax<<<NN / 4, 256, 0, stream>>>(h1, b3, out);
}

// Round 2
// 1153.573 us; speedup vs baseline: 6.0920x; 6.0920x over previous
//
#include <hip/hip_runtime.h>
#include <hip/hip_bf16.h>

#define NN 100000
#define NE 1600000
// IN_CH=500, HID=128, OUT_CH=40

#define SCAN_E 1024
#define NBLK ((NN + SCAN_E - 1) / SCAN_E)  // 98

// ---------------- graph norm + CSR build ----------------
__global__ __launch_bounds__(256) void k_deg_cnt(const int* __restrict__ ei,
                                                 const float* __restrict__ ea,
                                                 float* __restrict__ deg,
                                                 int* __restrict__ cnt) {
    int e = blockIdx.x * 256 + threadIdx.x;
    if (e < NE) {
        int d = ei[NE + e];
        unsafeAtomicAdd(&deg[d], ea[e]);
        atomicAdd(&cnt[d], 1);
    }
}

__global__ __launch_bounds__(256) void k_dinv(const float* __restrict__ deg,
                                              float* __restrict__ dinv) {
    int i = blockIdx.x * 256 + threadIdx.x;
    if (i < NN) {
        float d = deg[i] + 1.0f;  // + self-loop weight 1
        dinv[i] = rsqrtf(d);
    }
}

// block-local exclusive scan of cnt (1024 elems/block), block sums -> part
__global__ __launch_bounds__(256) void k_scan1(const int* __restrict__ cnt,
                                               int* __restrict__ row_ptr,
                                               int* __restrict__ part) {
    __shared__ int ts[256];
    const int tid = threadIdx.x;
    int base = blockIdx.x * SCAN_E + tid * 4;
    int v[4];
    int ssum = 0;
#pragma unroll
    for (int j = 0; j < 4; j++) {
        v[j] = (base + j < NN) ? cnt[base + j] : 0;
        ssum += v[j];
    }
    ts[tid] = ssum;
    __syncthreads();
    for (int o = 1; o < 256; o <<= 1) {
        int t = (tid >= o) ? ts[tid - o] : 0;
        __syncthreads();
        ts[tid] += t;
        __syncthreads();
    }
    int excl = ts[tid] - ssum;
#pragma unroll
    for (int j = 0; j < 4; j++) {
        if (base + j < NN) row_ptr[base + j] = excl;
        excl += v[j];
    }
    if (tid == 255) part[blockIdx.x] = ts[255];
}

__global__ void k_scan2(int* __restrict__ part) {
    if (threadIdx.x == 0) {
        int acc = 0;
        for (int b = 0; b < NBLK; b++) { int t = part[b]; part[b] = acc; acc += t; }
    }
}

// add block offsets; zero cnt (reused as scatter cursor); cap row_ptr
__global__ __launch_bounds__(256) void k_scan3(int* __restrict__ row_ptr,
                                               const int* __restrict__ part,
                                               int* __restrict__ cnt) {
    int base = blockIdx.x * SCAN_E + threadIdx.x * 4;
    int off = part[blockIdx.x];
#pragma unroll
    for (int j = 0; j < 4; j++)
        if (base + j < NN) { row_ptr[base + j] += off; cnt[base + j] = 0; }
    if (blockIdx.x == 0 && threadIdx.x == 0) row_ptr[NN] = NE;
}

// scatter edges into CSR slots; csr = (src, norm-weight) packed 8B
__global__ __launch_bounds__(256) void k_scatter(const int* __restrict__ ei,
                                                 const float* __restrict__ ea,
                                                 const float* __restrict__ dinv,
                                                 const int* __restrict__ row_ptr,
                                                 int* __restrict__ cursor,
                                                 int2* __restrict__ csr) {
    int e = blockIdx.x * 256 + threadIdx.x;
    if (e >= NE) return;
    int s = ei[e], d = ei[NE + e];
    int pos = row_ptr[d] + atomicAdd(&cursor[d], 1);
    float w = dinv[s] * ea[e] * dinv[d];
    csr[pos] = make_int2(s, __float_as_int(w));
}

// ---------------- fp32 GEMM, N=128 ----------------
template <int K, int KT>
__global__ __launch_bounds__(256) void k_gemm128(const float* __restrict__ X,
                                                 const float* __restrict__ W,
                                                 float* __restrict__ Out) {
    __shared__ float xs[KT][32];
    const int tid = threadIdx.x;
    const int col = tid & 127;
    const int rbase = (tid >> 7) * 16;
    const int row0 = blockIdx.x * 32;

    float acc[16];
#pragma unroll
    for (int i = 0; i < 16; i++) acc[i] = 0.f;

    for (int kt = 0; kt < K; kt += KT) {
        __syncthreads();
        for (int idx = tid; idx < KT * 32; idx += 256) {
            int r = idx & 31;
            int k = idx >> 5;
            xs[k][r] = X[(size_t)(row0 + r) * K + kt + k];
        }
        __syncthreads();
#pragma unroll 2
        for (int k = 0; k < KT; k++) {
            float w = W[(size_t)(kt + k) * 128 + col];
            const float* xr = &xs[k][rbase];
#pragma unroll
            for (int i = 0; i < 16; i++) acc[i] = fmaf(xr[i], w, acc[i]);
        }
    }
#pragma unroll
    for (int i = 0; i < 16; i++)
        Out[(size_t)(row0 + rbase + i) * 128 + col] = acc[i];
}

// ---------------- fp32 GEMM, K=128, N=40 ----------------
__global__ __launch_bounds__(256) void k_gemm40(const float* __restrict__ X,
                                                const float* __restrict__ W,
                                                float* __restrict__ Out) {
    __shared__ float xs[128][32];
    const int tid = threadIdx.x;
    const int col = tid & 63;
    const int rbase = (tid >> 6) * 8;
    const int row0 = blockIdx.x * 32;

    for (int idx = tid; idx < 128 * 32; idx += 256) {
        int r = idx & 31;
        int k = idx >> 5;
        xs[k][r] = X[(size_t)(row0 + r) * 128 + k];
    }
    __syncthreads();

    float acc[8];
#pragma unroll
    for (int i = 0; i < 8; i++) acc[i] = 0.f;

#pragma unroll 2
    for (int k = 0; k < 128; k++) {
        float w = (col < 40) ? W[k * 40 + col] : 0.f;
        const float* xr = &xs[k][rbase];
#pragma unroll
        for (int i = 0; i < 8; i++) acc[i] = fmaf(xr[i], w, acc[i]);
    }
    if (col < 40) {
#pragma unroll
        for (int i = 0; i < 8; i++)
            Out[(size_t)(row0 + rbase + i) * 40 + col] = acc[i];
    }
}

// ---------------- CSR pull aggregation, 128 ch ----------------
// 32 threads (float4 each) per node; 8 nodes per 256-block.
// MODE 1: out = relu(acc + b)        MODE 2: out = relu(acc + b) + R[row]
template <int MODE>
__global__ __launch_bounds__(256) void k_pull128(const float* __restrict__ H,
                                                 const int* __restrict__ row_ptr,
                                                 const int2* __restrict__ csr,
                                                 const float* __restrict__ dinv,
                                                 const float* __restrict__ b,
                                                 const float* __restrict__ R,
                                                 float* __restrict__ Out) {
    int node = blockIdx.x * 8 + (threadIdx.x >> 5);
    int cg = threadIdx.x & 31;
    float dv = dinv[node];
    float sw = dv * dv;  // self-loop weight
    const float4* hrow = reinterpret_cast<const float4*>(H + (size_t)node * 128);
    float4 h = hrow[cg];
    float4 acc;
    acc.x = h.x * sw; acc.y = h.y * sw; acc.z = h.z * sw; acc.w = h.w * sw;

    int e0 = row_ptr[node], e1 = row_ptr[node + 1];
    for (int e = e0; e < e1; e++) {
        int2 sv = csr[e];
        float w = __int_as_float(sv.y);
        float4 g = reinterpret_cast<const float4*>(H + (size_t)sv.x * 128)[cg];
        acc.x = fmaf(w, g.x, acc.x);
        acc.y = fmaf(w, g.y, acc.y);
        acc.z = fmaf(w, g.z, acc.z);
        acc.w = fmaf(w, g.w, acc.w);
    }

    float4 bb = reinterpret_cast<const float4*>(b)[cg];
    float4 o;
    o.x = fmaxf(acc.x + bb.x, 0.f);
    o.y = fmaxf(acc.y + bb.y, 0.f);
    o.z = fmaxf(acc.z + bb.z, 0.f);
    o.w = fmaxf(acc.w + bb.w, 0.f);
    if (MODE == 2) {
        float4 r = reinterpret_cast<const float4*>(R + (size_t)node * 128)[cg];
        o.x += r.x; o.y += r.y; o.z += r.z; o.w += r.w;
    }
    reinterpret_cast<float4*>(Out + (size_t)node * 128)[cg] = o;
}

// ---------------- layer 3: pull(40ch) + bias + log_softmax fused ----------------
// one wave per node; lanes 0..39 own one channel each
__global__ __launch_bounds__(256) void k_pull40_lsm(const float* __restrict__ G,
                                                    const int* __restrict__ row_ptr,
                                                    const int2* __restrict__ csr,
                                                    const float* __restrict__ dinv,
                                                    const float* __restrict__ b3,
                                                    float* __restrict__ out) {
    int node = blockIdx.x * 4 + (threadIdx.x >> 6);
    int lane = threadIdx.x & 63;
    float dv = dinv[node];
    float sw = dv * dv;
    float acc = 0.f;
    if (lane < 40) acc = G[(size_t)node * 40 + lane] * sw;
    int e0 = row_ptr[node], e1 = row_ptr[node + 1];
    for (int e = e0; e < e1; e++) {
        int2 sv = csr[e];
        float w = __int_as_float(sv.y);
        if (lane < 40) acc = fmaf(w, G[(size_t)sv.x * 40 + lane], acc);
    }
    float v = (lane < 40) ? acc + b3[lane] : -1e30f;
    float m = v;
    for (int o = 32; o; o >>= 1) m = fmaxf(m, __shfl_xor(m, o));
    float e = (lane < 40) ? expf(v - m) : 0.f;
    float ssum = e;
    for (int o = 32; o; o >>= 1) ssum += __shfl_xor(ssum, o);
    float ls = logf(ssum);
    if (lane < 40) out[(size_t)node * 40 + lane] = v - m - ls;
}

// ---------------- launch ----------------
extern "C" void kernel_launch(void* const* d_in, const int* in_sizes, int n_in,
                              void* d_out, int out_size, void* d_ws, size_t ws_size,
                              hipStream_t stream) {
    const float* x  = (const float*)d_in[0];
    const int*   ei = (const int*)d_in[1];   // [2, NE] int32
    const float* ea = (const float*)d_in[2];
    const float* W1 = (const float*)d_in[3];
    const float* b1 = (const float*)d_in[4];
    const float* W2 = (const float*)d_in[5];
    const float* b2 = (const float*)d_in[6];
    const float* W3 = (const float*)d_in[7];
    const float* b3 = (const float*)d_in[8];
    float* out = (float*)d_out;

    // workspace carve-up
    float* deg     = (float*)d_ws;                 // NN f32
    int*   cnt     = (int*)(deg + NN);             // NN i32 (then scatter cursor)
    float* dinv    = (float*)(cnt + NN);           // NN f32
    int*   row_ptr = (int*)(dinv + NN);            // NN+1 (pad 8)
    int*   part    = row_ptr + NN + 8;             // NBLK (pad 128)
    int2*  csr     = (int2*)(part + 128);          // NE int2
    float* H       = (float*)(csr + NE);           // NN*128
    float* h1      = H + (size_t)NN * 128;         // NN*128

    // ---- CSR build + norm
    hipMemsetAsync(deg, 0, NN * 8, stream);  // zeroes deg AND cnt (adjacent)
    k_deg_cnt<<<(NE + 255) / 256, 256, 0, stream>>>(ei, ea, deg, cnt);
    k_dinv<<<(NN + 255) / 256, 256, 0, stream>>>(deg, dinv);
    k_scan1<<<NBLK, 256, 0, stream>>>(cnt, row_ptr, part);
    k_scan2<<<1, 64, 0, stream>>>(part);
    k_scan3<<<NBLK, 256, 0, stream>>>(row_ptr, part, cnt);  // also zeroes cnt
    k_scatter<<<(NE + 255) / 256, 256, 0, stream>>>(ei, ea, dinv, row_ptr, cnt, csr);

    // ---- layer 1: H = X @ W1 ; h1 = relu(pull(H) + b1)
    k_gemm128<500, 50><<<NN / 32, 256, 0, stream>>>(x, W1, H);
    k_pull128<1><<<NN / 8, 256, 0, stream>>>(H, row_ptr, csr, dinv, b1, nullptr, h1);

    // ---- layer 2: H = h1 @ W2 ; h1 = relu(pull(H) + b2) + h1   (in-place ok: own-row RMW)
    k_gemm128<128, 64><<<NN / 32, 256, 0, stream>>>(h1, W2, H);
    k_pull128<2><<<NN / 8, 256, 0, stream>>>(H, row_ptr, csr, dinv, b2, h1, h1);

    // ---- layer 3: G3 = h1 @ W3 (into H) ; out = log_softmax(pull(G3) + b3)
    k_gemm40<<<NN / 32, 256, 0, stream>>>(h1, W3, H);
    k_pull40_lsm<<<NN / 4, 256, 0, stream>>>(H, row_ptr, csr, dinv, b3, out);
}

// Round 3
// 917.234 us; speedup vs baseline: 7.6617x; 1.2577x over previous
//
#include <hip/hip_runtime.h>
#include <hip/hip_bf16.h>

#define NN 100000
#define NE 1600000
// IN_CH=500, HID=128, OUT_CH=40

#define SCAN_E 1024
#define NBLK ((NN + SCAN_E - 1) / SCAN_E)  // 98

using f32x4 = __attribute__((ext_vector_type(4))) float;
using bf16x8 = __attribute__((ext_vector_type(8))) short;  // 8 bf16 in 4 VGPRs

__device__ inline unsigned short f2bf(float f) {
    unsigned u = __float_as_uint(f);
    unsigned r = (u + 0x7fffu + ((u >> 16) & 1u)) >> 16;  // RNE
    return (unsigned short)r;
}

// ---------------- graph norm + CSR build ----------------
__global__ __launch_bounds__(256) void k_deg_cnt(const int* __restrict__ ei,
                                                 const float* __restrict__ ea,
                                                 float* __restrict__ deg,
                                                 int* __restrict__ cnt) {
    int e = blockIdx.x * 256 + threadIdx.x;
    if (e < NE) {
        int d = ei[NE + e];
        unsafeAtomicAdd(&deg[d], ea[e]);
        atomicAdd(&cnt[d], 1);
    }
}

__global__ __launch_bounds__(256) void k_dinv(const float* __restrict__ deg,
                                              float* __restrict__ dinv) {
    int i = blockIdx.x * 256 + threadIdx.x;
    if (i < NN) {
        float d = deg[i] + 1.0f;  // + self-loop weight 1
        dinv[i] = rsqrtf(d);
    }
}

__global__ __launch_bounds__(256) void k_scan1(const int* __restrict__ cnt,
                                               int* __restrict__ row_ptr,
                                               int* __restrict__ part) {
    __shared__ int ts[256];
    const int tid = threadIdx.x;
    int base = blockIdx.x * SCAN_E + tid * 4;
    int v[4];
    int ssum = 0;
#pragma unroll
    for (int j = 0; j < 4; j++) {
        v[j] = (base + j < NN) ? cnt[base + j] : 0;
        ssum += v[j];
    }
    ts[tid] = ssum;
    __syncthreads();
    for (int o = 1; o < 256; o <<= 1) {
        int t = (tid >= o) ? ts[tid - o] : 0;
        __syncthreads();
        ts[tid] += t;
        __syncthreads();
    }
    int excl = ts[tid] - ssum;
#pragma unroll
    for (int j = 0; j < 4; j++) {
        if (base + j < NN) row_ptr[base + j] = excl;
        excl += v[j];
    }
    if (tid == 255) part[blockIdx.x] = ts[255];
}

__global__ void k_scan2(int* __restrict__ part) {
    if (threadIdx.x == 0) {
        int acc = 0;
        for (int b = 0; b < NBLK; b++) { int t = part[b]; part[b] = acc; acc += t; }
    }
}

__global__ __launch_bounds__(256) void k_scan3(int* __restrict__ row_ptr,
                                               const int* __restrict__ part,
                                               int* __restrict__ cnt) {
    int base = blockIdx.x * SCAN_E + threadIdx.x * 4;
    int off = part[blockIdx.x];
#pragma unroll
    for (int j = 0; j < 4; j++)
        if (base + j < NN) { row_ptr[base + j] += off; cnt[base + j] = 0; }
    if (blockIdx.x == 0 && threadIdx.x == 0) row_ptr[NN] = NE;
}

__global__ __launch_bounds__(256) void k_scatter(const int* __restrict__ ei,
                                                 const float* __restrict__ ea,
                                                 const float* __restrict__ dinv,
                                                 const int* __restrict__ row_ptr,
                                                 int* __restrict__ cursor,
                                                 int2* __restrict__ csr) {
    int e = blockIdx.x * 256 + threadIdx.x;
    if (e >= NE) return;
    int s = ei[e], d = ei[NE + e];
    int pos = row_ptr[d] + atomicAdd(&cursor[d], 1);
    float w = dinv[s] * ea[e] * dinv[d];
    csr[pos] = make_int2(s, __float_as_int(w));
}

// ---------------- W pack: fragment-ordered bf16 ----------------
// Wp layout: [(ks*8 + nt)*64 + lane] -> 8 bf16: W[ks*32 + (lane>>4)*8 + j][nt*16 + (lane&15)]
__global__ __launch_bounds__(256) void k_packW(const float* __restrict__ W,
                                               short* __restrict__ Wp,
                                               int K, int total) {
    int t = blockIdx.x * 256 + threadIdx.x;
    if (t >= total) return;
    int lane = t & 63;
    int nt = (t >> 6) & 7;
    int ks = t >> 9;
    int col = nt * 16 + (lane & 15);
    int kb = ks * 32 + ((lane >> 4) << 3);
    bf16x8 v;
#pragma unroll
    for (int j = 0; j < 8; j++) {
        int k = kb + j;
        v[j] = (k < K) ? (short)f2bf(W[(size_t)k * 128 + col]) : (short)0;
    }
    reinterpret_cast<bf16x8*>(Wp)[t] = v;
}

// ---------------- MFMA GEMM, N=128, A fp32 from global (cvt on the fly) ----------------
// 512 threads = 8 waves; wave w owns rows blk*128 + w*16, all 128 cols (8 n-tiles).
template <int KLIM, int KSTEPS, bool TAIL>
__global__ __launch_bounds__(512) void k_gemm_mfma(const float* __restrict__ X,
                                                   const short* __restrict__ Wp,
                                                   float* __restrict__ Out) {
    const int lane = threadIdx.x & 63;
    const int wave = threadIdx.x >> 6;
    const int row0 = blockIdx.x * 128 + wave * 16;
    const int arow = row0 + (lane & 15);
    const int kgrp = (lane >> 4) << 3;
    const bool rvalid = arow < NN;
    const float* aptr = X + (size_t)arow * KLIM + kgrp;
    const bf16x8* wp = reinterpret_cast<const bf16x8*>(Wp);

    f32x4 acc[8];
#pragma unroll
    for (int nt = 0; nt < 8; nt++) acc[nt] = (f32x4){0.f, 0.f, 0.f, 0.f};

    const int FULL = TAIL ? (KSTEPS - 1) : KSTEPS;
#pragma unroll 2
    for (int ks = 0; ks < FULL; ks++) {
        bf16x8 af;
        if (rvalid) {
            float4 f0 = *reinterpret_cast<const float4*>(aptr + ks * 32);
            float4 f1 = *reinterpret_cast<const float4*>(aptr + ks * 32 + 4);
            af[0] = (short)f2bf(f0.x); af[1] = (short)f2bf(f0.y);
            af[2] = (short)f2bf(f0.z); af[3] = (short)f2bf(f0.w);
            af[4] = (short)f2bf(f1.x); af[5] = (short)f2bf(f1.y);
            af[6] = (short)f2bf(f1.z); af[7] = (short)f2bf(f1.w);
        } else {
#pragma unroll
            for (int j = 0; j < 8; j++) af[j] = 0;
        }
#pragma unroll
        for (int nt = 0; nt < 8; nt++) {
            bf16x8 bf = wp[(ks * 8 + nt) * 64 + lane];
            acc[nt] = __builtin_amdgcn_mfma_f32_16x16x32_bf16(af, bf, acc[nt], 0, 0, 0);
        }
    }
    if (TAIL) {
        const int ks = KSTEPS - 1;
        bf16x8 af;
#pragma unroll
        for (int j = 0; j < 8; j++) {
            int k = ks * 32 + kgrp + j;
            float v = (rvalid && k < KLIM) ? aptr[ks * 32 + j] : 0.f;
            af[j] = (short)f2bf(v);
        }
#pragma unroll
        for (int nt = 0; nt < 8; nt++) {
            bf16x8 bf = wp[(ks * 8 + nt) * 64 + lane];
            acc[nt] = __builtin_amdgcn_mfma_f32_16x16x32_bf16(af, bf, acc[nt], 0, 0, 0);
        }
    }

    // D: col = nt*16 + (lane&15), row = row0 + (lane>>4)*4 + r
    const int rbase = row0 + ((lane >> 4) << 2);
    const int cbase = lane & 15;
#pragma unroll
    for (int r = 0; r < 4; r++) {
        int orow = rbase + r;
        if (orow < NN) {
            float* orow_p = Out + (size_t)orow * 128 + cbase;
#pragma unroll
            for (int nt = 0; nt < 8; nt++) orow_p[nt * 16] = acc[nt][r];
        }
    }
}

// ---------------- fp32 GEMM, K=128, N=40 ----------------
__global__ __launch_bounds__(256) void k_gemm40(const float* __restrict__ X,
                                                const float* __restrict__ W,
                                                float* __restrict__ Out) {
    __shared__ float xs[128][32];
    const int tid = threadIdx.x;
    const int col = tid & 63;
    const int rbase = (tid >> 6) * 8;
    const int row0 = blockIdx.x * 32;

    for (int idx = tid; idx < 128 * 32; idx += 256) {
        int r = idx & 31;
        int k = idx >> 5;
        xs[k][r] = X[(size_t)(row0 + r) * 128 + k];
    }
    __syncthreads();

    float acc[8];
#pragma unroll
    for (int i = 0; i < 8; i++) acc[i] = 0.f;

#pragma unroll 2
    for (int k = 0; k < 128; k++) {
        float w = (col < 40) ? W[k * 40 + col] : 0.f;
        const float* xr = &xs[k][rbase];
#pragma unroll
        for (int i = 0; i < 8; i++) acc[i] = fmaf(xr[i], w, acc[i]);
    }
    if (col < 40) {
#pragma unroll
        for (int i = 0; i < 8; i++)
            Out[(size_t)(row0 + rbase + i) * 40 + col] = acc[i];
    }
}

// ---------------- CSR pull aggregation, 128 ch ----------------
template <int MODE>
__global__ __launch_bounds__(256) void k_pull128(const float* __restrict__ H,
                                                 const int* __restrict__ row_ptr,
                                                 const int2* __restrict__ csr,
                                                 const float* __restrict__ dinv,
                                                 const float* __restrict__ b,
                                                 const float* __restrict__ R,
                                                 float* __restrict__ Out) {
    int node = blockIdx.x * 8 + (threadIdx.x >> 5);
    int cg = threadIdx.x & 31;
    float dv = dinv[node];
    float sw = dv * dv;  // self-loop weight
    const float4* hrow = reinterpret_cast<const float4*>(H + (size_t)node * 128);
    float4 h = hrow[cg];
    float4 acc;
    acc.x = h.x * sw; acc.y = h.y * sw; acc.z = h.z * sw; acc.w = h.w * sw;

    int e0 = row_ptr[node], e1 = row_ptr[node + 1];
    for (int e = e0; e < e1; e++) {
        int2 sv = csr[e];
        float w = __int_as_float(sv.y);
        float4 g = reinterpret_cast<const float4*>(H + (size_t)sv.x * 128)[cg];
        acc.x = fmaf(w, g.x, acc.x);
        acc.y = fmaf(w, g.y, acc.y);
        acc.z = fmaf(w, g.z, acc.z);
        acc.w = fmaf(w, g.w, acc.w);
    }

    float4 bb = reinterpret_cast<const float4*>(b)[cg];
    float4 o;
    o.x = fmaxf(acc.x + bb.x, 0.f);
    o.y = fmaxf(acc.y + bb.y, 0.f);
    o.z = fmaxf(acc.z + bb.z, 0.f);
    o.w = fmaxf(acc.w + bb.w, 0.f);
    if (MODE == 2) {
        float4 r = reinterpret_cast<const float4*>(R + (size_t)node * 128)[cg];
        o.x += r.x; o.y += r.y; o.z += r.z; o.w += r.w;
    }
    reinterpret_cast<float4*>(Out + (size_t)node * 128)[cg] = o;
}

// ---------------- layer 3: pull(40ch) + bias + log_softmax fused ----------------
__global__ __launch_bounds__(256) void k_pull40_lsm(const float* __restrict__ G,
                                                    const int* __restrict__ row_ptr,
                                                    const int2* __restrict__ csr,
                                                    const float* __restrict__ dinv,
                                                    const float* __restrict__ b3,
                                                    float* __restrict__ out) {
    int node = blockIdx.x * 4 + (threadIdx.x >> 6);
    int lane = threadIdx.x & 63;
    float dv = dinv[node];
    float sw = dv * dv;
    float acc = 0.f;
    if (lane < 40) acc = G[(size_t)node * 40 + lane] * sw;
    int e0 = row_ptr[node], e1 = row_ptr[node + 1];
    for (int e = e0; e < e1; e++) {
        int2 sv = csr[e];
        float w = __int_as_float(sv.y);
        if (lane < 40) acc = fmaf(w, G[(size_t)sv.x * 40 + lane], acc);
    }
    float v = (lane < 40) ? acc + b3[lane] : -1e30f;
    float m = v;
    for (int o = 32; o; o >>= 1) m = fmaxf(m, __shfl_xor(m, o));
    float e = (lane < 40) ? expf(v - m) : 0.f;
    float ssum = e;
    for (int o = 32; o; o >>= 1) ssum += __shfl_xor(ssum, o);
    float ls = logf(ssum);
    if (lane < 40) out[(size_t)node * 40 + lane] = v - m - ls;
}

// ---------------- launch ----------------
extern "C" void kernel_launch(void* const* d_in, const int* in_sizes, int n_in,
                              void* d_out, int out_size, void* d_ws, size_t ws_size,
                              hipStream_t stream) {
    const float* x  = (const float*)d_in[0];
    const int*   ei = (const int*)d_in[1];   // [2, NE] int32
    const float* ea = (const float*)d_in[2];
    const float* W1 = (const float*)d_in[3];
    const float* b1 = (const float*)d_in[4];
    const float* W2 = (const float*)d_in[5];
    const float* b2 = (const float*)d_in[6];
    const float* W3 = (const float*)d_in[7];
    const float* b3 = (const float*)d_in[8];
    float* out = (float*)d_out;

    // workspace carve-up (all region sizes multiples of 16 B)
    short* Wp1     = (short*)d_ws;                 // 16*8*64*8 = 65536 bf16 (128 KB)
    short* Wp2     = Wp1 + 65536;                  // 4*8*64*8 = 16384 bf16 (32 KB)
    float* deg     = (float*)(Wp2 + 16384);        // NN f32
    int*   cnt     = (int*)(deg + NN);             // NN i32 (then scatter cursor)
    float* dinv    = (float*)(cnt + NN);           // NN f32
    int*   row_ptr = (int*)(dinv + NN);            // NN+1 (pad 8)
    int*   part    = row_ptr + NN + 8;             // NBLK (pad 128)
    int2*  csr     = (int2*)(part + 128);          // NE int2
    float* H       = (float*)(csr + NE);           // NN*128
    float* h1      = H + (size_t)NN * 128;         // NN*128

    // ---- CSR build + norm + W packing
    hipMemsetAsync(deg, 0, NN * 8, stream);  // zeroes deg AND cnt (adjacent)
    k_deg_cnt<<<(NE + 255) / 256, 256, 0, stream>>>(ei, ea, deg, cnt);
    k_dinv<<<(NN + 255) / 256, 256, 0, stream>>>(deg, dinv);
    k_scan1<<<NBLK, 256, 0, stream>>>(cnt, row_ptr, part);
    k_scan2<<<1, 64, 0, stream>>>(part);
    k_scan3<<<NBLK, 256, 0, stream>>>(row_ptr, part, cnt);  // also zeroes cnt
    k_scatter<<<(NE + 255) / 256, 256, 0, stream>>>(ei, ea, dinv, row_ptr, cnt, csr);
    k_packW<<<32, 256, 0, stream>>>(W1, Wp1, 500, 16 * 8 * 64);
    k_packW<<<8, 256, 0, stream>>>(W2, Wp2, 128, 4 * 8 * 64);

    const int GBLK = (NN + 127) / 128;  // 782

    // ---- layer 1: H = X @ W1 (MFMA bf16) ; h1 = relu(pull(H) + b1)
    k_gemm_mfma<500, 16, true><<<GBLK, 512, 0, stream>>>(x, Wp1, H);
    k_pull128<1><<<NN / 8, 256, 0, stream>>>(H, row_ptr, csr, dinv, b1, nullptr, h1);

    // ---- layer 2: H = h1 @ W2 (MFMA bf16) ; h1 = relu(pull(H) + b2) + h1
    k_gemm_mfma<128, 4, false><<<GBLK, 512, 0, stream>>>(h1, Wp2, H);
    k_pull128<2><<<NN / 8, 256, 0, stream>>>(H, row_ptr, csr, dinv, b2, h1, h1);

    // ---- layer 3: G3 = h1 @ W3 (into H, fp32) ; out = log_softmax(pull(G3) + b3)
    k_gemm40<<<NN / 32, 256, 0, stream>>>(h1, W3, H);
    k_pull40_lsm<<<NN / 4, 256, 0, stream>>>(H, row_ptr, csr, dinv, b3, out);
}

// Round 4
// 834.454 us; speedup vs baseline: 8.4218x; 1.0992x over previous
//
#include <hip/hip_runtime.h>
#include <hip/hip_bf16.h>

#define NN 100000
#define NE 1600000
// IN_CH=500, HID=128, OUT_CH=40

#define SCAN_E 1024
#define NBLK ((NN + SCAN_E - 1) / SCAN_E)  // 98

using f32x4 = __attribute__((ext_vector_type(4))) float;
using bf16x8 = __attribute__((ext_vector_type(8))) short;  // 8 bf16 in 4 VGPRs

__device__ inline unsigned short f2bf(float f) {
    unsigned u = __float_as_uint(f);
    unsigned r = (u + 0x7fffu + ((u >> 16) & 1u)) >> 16;  // RNE
    return (unsigned short)r;
}

// ---------------- graph norm + CSR build ----------------
__global__ __launch_bounds__(256) void k_deg_cnt(const int* __restrict__ ei,
                                                 const float* __restrict__ ea,
                                                 float* __restrict__ deg,
                                                 int* __restrict__ cnt) {
    int e = blockIdx.x * 256 + threadIdx.x;
    if (e < NE) {
        int d = ei[NE + e];
        unsafeAtomicAdd(&deg[d], ea[e]);
        atomicAdd(&cnt[d], 1);
    }
}

__global__ __launch_bounds__(256) void k_dinv(const float* __restrict__ deg,
                                              float* __restrict__ dinv) {
    int i = blockIdx.x * 256 + threadIdx.x;
    if (i < NN) {
        float d = deg[i] + 1.0f;  // + self-loop weight 1
        dinv[i] = rsqrtf(d);
    }
}

__global__ __launch_bounds__(256) void k_scan1(const int* __restrict__ cnt,
                                               int* __restrict__ row_ptr,
                                               int* __restrict__ part) {
    __shared__ int ts[256];
    const int tid = threadIdx.x;
    int base = blockIdx.x * SCAN_E + tid * 4;
    int v[4];
    int ssum = 0;
#pragma unroll
    for (int j = 0; j < 4; j++) {
        v[j] = (base + j < NN) ? cnt[base + j] : 0;
        ssum += v[j];
    }
    ts[tid] = ssum;
    __syncthreads();
    for (int o = 1; o < 256; o <<= 1) {
        int t = (tid >= o) ? ts[tid - o] : 0;
        __syncthreads();
        ts[tid] += t;
        __syncthreads();
    }
    int excl = ts[tid] - ssum;
#pragma unroll
    for (int j = 0; j < 4; j++) {
        if (base + j < NN) row_ptr[base + j] = excl;
        excl += v[j];
    }
    if (tid == 255) part[blockIdx.x] = ts[255];
}

__global__ void k_scan2(int* __restrict__ part) {
    if (threadIdx.x == 0) {
        int acc = 0;
        for (int b = 0; b < NBLK; b++) { int t = part[b]; part[b] = acc; acc += t; }
    }
}

__global__ __launch_bounds__(256) void k_scan3(int* __restrict__ row_ptr,
                                               const int* __restrict__ part,
                                               int* __restrict__ cnt) {
    int base = blockIdx.x * SCAN_E + threadIdx.x * 4;
    int off = part[blockIdx.x];
#pragma unroll
    for (int j = 0; j < 4; j++)
        if (base + j < NN) { row_ptr[base + j] += off; cnt[base + j] = 0; }
    if (blockIdx.x == 0 && threadIdx.x == 0) row_ptr[NN] = NE;
}

__global__ __launch_bounds__(256) void k_scatter(const int* __restrict__ ei,
                                                 const float* __restrict__ ea,
                                                 const float* __restrict__ dinv,
                                                 const int* __restrict__ row_ptr,
                                                 int* __restrict__ cursor,
                                                 int2* __restrict__ csr) {
    int e = blockIdx.x * 256 + threadIdx.x;
    if (e >= NE) return;
    int s = ei[e], d = ei[NE + e];
    int pos = row_ptr[d] + atomicAdd(&cursor[d], 1);
    float w = dinv[s] * ea[e] * dinv[d];
    csr[pos] = make_int2(s, __float_as_int(w));
}

// ---------------- W pack: fragment-ordered bf16 ----------------
__global__ __launch_bounds__(256) void k_packW(const float* __restrict__ W,
                                               short* __restrict__ Wp,
                                               int K, int total) {
    int t = blockIdx.x * 256 + threadIdx.x;
    if (t >= total) return;
    int lane = t & 63;
    int nt = (t >> 6) & 7;
    int ks = t >> 9;
    int col = nt * 16 + (lane & 15);
    int kb = ks * 32 + ((lane >> 4) << 3);
    bf16x8 v;
#pragma unroll
    for (int j = 0; j < 8; j++) {
        int k = kb + j;
        v[j] = (k < K) ? (short)f2bf(W[(size_t)k * 128 + col]) : (short)0;
    }
    reinterpret_cast<bf16x8*>(Wp)[t] = v;
}

// ---------------- MFMA GEMM, N=128 ----------------
template <int KLIM, int KSTEPS, bool TAIL>
__global__ __launch_bounds__(512) void k_gemm_mfma(const float* __restrict__ X,
                                                   const short* __restrict__ Wp,
                                                   float* __restrict__ Out) {
    const int lane = threadIdx.x & 63;
    const int wave = threadIdx.x >> 6;
    const int row0 = blockIdx.x * 128 + wave * 16;
    const int arow = row0 + (lane & 15);
    const int kgrp = (lane >> 4) << 3;
    const bool rvalid = arow < NN;
    const float* aptr = X + (size_t)arow * KLIM + kgrp;
    const bf16x8* wp = reinterpret_cast<const bf16x8*>(Wp);

    f32x4 acc[8];
#pragma unroll
    for (int nt = 0; nt < 8; nt++) acc[nt] = (f32x4){0.f, 0.f, 0.f, 0.f};

    const int FULL = TAIL ? (KSTEPS - 1) : KSTEPS;
#pragma unroll 2
    for (int ks = 0; ks < FULL; ks++) {
        bf16x8 af;
        if (rvalid) {
            float4 f0 = *reinterpret_cast<const float4*>(aptr + ks * 32);
            float4 f1 = *reinterpret_cast<const float4*>(aptr + ks * 32 + 4);
            af[0] = (short)f2bf(f0.x); af[1] = (short)f2bf(f0.y);
            af[2] = (short)f2bf(f0.z); af[3] = (short)f2bf(f0.w);
            af[4] = (short)f2bf(f1.x); af[5] = (short)f2bf(f1.y);
            af[6] = (short)f2bf(f1.z); af[7] = (short)f2bf(f1.w);
        } else {
#pragma unroll
            for (int j = 0; j < 8; j++) af[j] = 0;
        }
#pragma unroll
        for (int nt = 0; nt < 8; nt++) {
            bf16x8 bf = wp[(ks * 8 + nt) * 64 + lane];
            acc[nt] = __builtin_amdgcn_mfma_f32_16x16x32_bf16(af, bf, acc[nt], 0, 0, 0);
        }
    }
    if (TAIL) {
        const int ks = KSTEPS - 1;
        bf16x8 af;
#pragma unroll
        for (int j = 0; j < 8; j++) {
            int k = ks * 32 + kgrp + j;
            float v = (rvalid && k < KLIM) ? aptr[ks * 32 + j] : 0.f;
            af[j] = (short)f2bf(v);
        }
#pragma unroll
        for (int nt = 0; nt < 8; nt++) {
            bf16x8 bf = wp[(ks * 8 + nt) * 64 + lane];
            acc[nt] = __builtin_amdgcn_mfma_f32_16x16x32_bf16(af, bf, acc[nt], 0, 0, 0);
        }
    }

    const int rbase = row0 + ((lane >> 4) << 2);
    const int cbase = lane & 15;
#pragma unroll
    for (int r = 0; r < 4; r++) {
        int orow = rbase + r;
        if (orow < NN) {
            float* orow_p = Out + (size_t)orow * 128 + cbase;
#pragma unroll
            for (int nt = 0; nt < 8; nt++) orow_p[nt * 16] = acc[nt][r];
        }
    }
}

// ---------------- fp32 GEMM, K=128, N=40 ----------------
__global__ __launch_bounds__(256) void k_gemm40(const float* __restrict__ X,
                                                const float* __restrict__ W,
                                                float* __restrict__ Out) {
    __shared__ float xs[128][32];
    const int tid = threadIdx.x;
    const int col = tid & 63;
    const int rbase = (tid >> 6) * 8;
    const int row0 = blockIdx.x * 32;

    for (int idx = tid; idx < 128 * 32; idx += 256) {
        int r = idx & 31;
        int k = idx >> 5;
        xs[k][r] = X[(size_t)(row0 + r) * 128 + k];
    }
    __syncthreads();

    float acc[8];
#pragma unroll
    for (int i = 0; i < 8; i++) acc[i] = 0.f;

#pragma unroll 2
    for (int k = 0; k < 128; k++) {
        float w = (col < 40) ? W[k * 40 + col] : 0.f;
        const float* xr = &xs[k][rbase];
#pragma unroll
        for (int i = 0; i < 8; i++) acc[i] = fmaf(xr[i], w, acc[i]);
    }
    if (col < 40) {
#pragma unroll
        for (int i = 0; i < 8; i++)
            Out[(size_t)(row0 + rbase + i) * 40 + col] = acc[i];
    }
}

// ---------------- CSR pull aggregation, 128 ch ----------------
// 32 lanes per node, 8 nodes/block. Cooperative edge-header load (1 coalesced
// int2 read per 32 edges) + shfl broadcast + 4-way unrolled independent gathers.
template <int MODE>
__global__ __launch_bounds__(256) void k_pull128(const float* __restrict__ H,
                                                 const int* __restrict__ row_ptr,
                                                 const int2* __restrict__ csr,
                                                 const float* __restrict__ dinv,
                                                 const float* __restrict__ b,
                                                 const float* __restrict__ R,
                                                 float* __restrict__ Out) {
    int node = blockIdx.x * 8 + (threadIdx.x >> 5);
    int cg = threadIdx.x & 31;
    const float4* H4 = reinterpret_cast<const float4*>(H);
    float dv = dinv[node];
    float sw = dv * dv;  // self-loop weight
    float4 h = H4[node * 32 + cg];
    float4 acc;
    acc.x = h.x * sw; acc.y = h.y * sw; acc.z = h.z * sw; acc.w = h.w * sw;

    int e0 = row_ptr[node], e1 = row_ptr[node + 1];
    for (int base = e0; base < e1; base += 32) {
        int n = e1 - base;
        if (n > 32) n = 32;
        int2 sv = (cg < n) ? csr[base + cg] : make_int2(0, 0);
        int j = 0;
        for (; j + 4 <= n; j += 4) {
            int s0 = __shfl(sv.x, j + 0, 32);
            int s1 = __shfl(sv.x, j + 1, 32);
            int s2 = __shfl(sv.x, j + 2, 32);
            int s3 = __shfl(sv.x, j + 3, 32);
            float w0 = __int_as_float(__shfl(sv.y, j + 0, 32));
            float w1 = __int_as_float(__shfl(sv.y, j + 1, 32));
            float w2 = __int_as_float(__shfl(sv.y, j + 2, 32));
            float w3 = __int_as_float(__shfl(sv.y, j + 3, 32));
            float4 g0 = H4[s0 * 32 + cg];
            float4 g1 = H4[s1 * 32 + cg];
            float4 g2 = H4[s2 * 32 + cg];
            float4 g3 = H4[s3 * 32 + cg];
            acc.x = fmaf(w0, g0.x, acc.x); acc.y = fmaf(w0, g0.y, acc.y);
            acc.z = fmaf(w0, g0.z, acc.z); acc.w = fmaf(w0, g0.w, acc.w);
            acc.x = fmaf(w1, g1.x, acc.x); acc.y = fmaf(w1, g1.y, acc.y);
            acc.z = fmaf(w1, g1.z, acc.z); acc.w = fmaf(w1, g1.w, acc.w);
            acc.x = fmaf(w2, g2.x, acc.x); acc.y = fmaf(w2, g2.y, acc.y);
            acc.z = fmaf(w2, g2.z, acc.z); acc.w = fmaf(w2, g2.w, acc.w);
            acc.x = fmaf(w3, g3.x, acc.x); acc.y = fmaf(w3, g3.y, acc.y);
            acc.z = fmaf(w3, g3.z, acc.z); acc.w = fmaf(w3, g3.w, acc.w);
        }
        for (; j < n; j++) {
            int s = __shfl(sv.x, j, 32);
            float w = __int_as_float(__shfl(sv.y, j, 32));
            float4 g = H4[s * 32 + cg];
            acc.x = fmaf(w, g.x, acc.x); acc.y = fmaf(w, g.y, acc.y);
            acc.z = fmaf(w, g.z, acc.z); acc.w = fmaf(w, g.w, acc.w);
        }
    }

    float4 bb = reinterpret_cast<const float4*>(b)[cg];
    float4 o;
    o.x = fmaxf(acc.x + bb.x, 0.f);
    o.y = fmaxf(acc.y + bb.y, 0.f);
    o.z = fmaxf(acc.z + bb.z, 0.f);
    o.w = fmaxf(acc.w + bb.w, 0.f);
    if (MODE == 2) {
        float4 r = reinterpret_cast<const float4*>(R)[node * 32 + cg];
        o.x += r.x; o.y += r.y; o.z += r.z; o.w += r.w;
    }
    reinterpret_cast<float4*>(Out)[node * 32 + cg] = o;
}

// ---------------- layer 3: pull(40ch) + bias + log_softmax fused ----------------
// one wave per node; cooperative 64-edge header loads + 4-way unrolled gathers
__global__ __launch_bounds__(256) void k_pull40_lsm(const float* __restrict__ G,
                                                    const int* __restrict__ row_ptr,
                                                    const int2* __restrict__ csr,
                                                    const float* __restrict__ dinv,
                                                    const float* __restrict__ b3,
                                                    float* __restrict__ out) {
    int node = blockIdx.x * 4 + (threadIdx.x >> 6);
    int lane = threadIdx.x & 63;
    const bool act = lane < 40;
    float dv = dinv[node];
    float sw = dv * dv;
    float acc = act ? G[node * 40 + lane] * sw : 0.f;

    int e0 = row_ptr[node], e1 = row_ptr[node + 1];
    for (int base = e0; base < e1; base += 64) {
        int n = e1 - base;
        if (n > 64) n = 64;
        int2 sv = (lane < n) ? csr[base + lane] : make_int2(0, 0);
        int j = 0;
        for (; j + 4 <= n; j += 4) {
            int s0 = __shfl(sv.x, j + 0);
            int s1 = __shfl(sv.x, j + 1);
            int s2 = __shfl(sv.x, j + 2);
            int s3 = __shfl(sv.x, j + 3);
            float w0 = __int_as_float(__shfl(sv.y, j + 0));
            float w1 = __int_as_float(__shfl(sv.y, j + 1));
            float w2 = __int_as_float(__shfl(sv.y, j + 2));
            float w3 = __int_as_float(__shfl(sv.y, j + 3));
            float g0 = act ? G[s0 * 40 + lane] : 0.f;
            float g1 = act ? G[s1 * 40 + lane] : 0.f;
            float g2 = act ? G[s2 * 40 + lane] : 0.f;
            float g3 = act ? G[s3 * 40 + lane] : 0.f;
            acc = fmaf(w0, g0, acc);
            acc = fmaf(w1, g1, acc);
            acc = fmaf(w2, g2, acc);
            acc = fmaf(w3, g3, acc);
        }
        for (; j < n; j++) {
            int s = __shfl(sv.x, j);
            float w = __int_as_float(__shfl(sv.y, j));
            float g = act ? G[s * 40 + lane] : 0.f;
            acc = fmaf(w, g, acc);
        }
    }

    float v = act ? acc + b3[lane] : -1e30f;
    float m = v;
    for (int o = 32; o; o >>= 1) m = fmaxf(m, __shfl_xor(m, o));
    float e = act ? expf(v - m) : 0.f;
    float ssum = e;
    for (int o = 32; o; o >>= 1) ssum += __shfl_xor(ssum, o);
    float ls = logf(ssum);
    if (act) out[node * 40 + lane] = v - m - ls;
}

// ---------------- launch ----------------
extern "C" void kernel_launch(void* const* d_in, const int* in_sizes, int n_in,
                              void* d_out, int out_size, void* d_ws, size_t ws_size,
                              hipStream_t stream) {
    const float* x  = (const float*)d_in[0];
    const int*   ei = (const int*)d_in[1];   // [2, NE] int32
    const float* ea = (const float*)d_in[2];
    const float* W1 = (const float*)d_in[3];
    const float* b1 = (const float*)d_in[4];
    const float* W2 = (const float*)d_in[5];
    const float* b2 = (const float*)d_in[6];
    const float* W3 = (const float*)d_in[7];
    const float* b3 = (const float*)d_in[8];
    float* out = (float*)d_out;

    // workspace carve-up (all region sizes multiples of 16 B)
    short* Wp1     = (short*)d_ws;                 // 65536 bf16 (128 KB)
    short* Wp2     = Wp1 + 65536;                  // 16384 bf16 (32 KB)
    float* deg     = (float*)(Wp2 + 16384);        // NN f32
    int*   cnt     = (int*)(deg + NN);             // NN i32 (then scatter cursor)
    float* dinv    = (float*)(cnt + NN);           // NN f32
    int*   row_ptr = (int*)(dinv + NN);            // NN+1 (pad 8)
    int*   part    = row_ptr + NN + 8;             // NBLK (pad 128)
    int2*  csr     = (int2*)(part + 128);          // NE int2
    float* H       = (float*)(csr + NE);           // NN*128
    float* h1      = H + (size_t)NN * 128;         // NN*128

    // ---- CSR build + norm + W packing
    hipMemsetAsync(deg, 0, NN * 8, stream);  // zeroes deg AND cnt (adjacent)
    k_deg_cnt<<<(NE + 255) / 256, 256, 0, stream>>>(ei, ea, deg, cnt);
    k_dinv<<<(NN + 255) / 256, 256, 0, stream>>>(deg, dinv);
    k_scan1<<<NBLK, 256, 0, stream>>>(cnt, row_ptr, part);
    k_scan2<<<1, 64, 0, stream>>>(part);
    k_scan3<<<NBLK, 256, 0, stream>>>(row_ptr, part, cnt);  // also zeroes cnt
    k_scatter<<<(NE + 255) / 256, 256, 0, stream>>>(ei, ea, dinv, row_ptr, cnt, csr);
    k_packW<<<32, 256, 0, stream>>>(W1, Wp1, 500, 16 * 8 * 64);
    k_packW<<<8, 256, 0, stream>>>(W2, Wp2, 128, 4 * 8 * 64);

    const int GBLK = (NN + 127) / 128;  // 782

    // ---- layer 1: H = X @ W1 (MFMA bf16) ; h1 = relu(pull(H) + b1)
    k_gemm_mfma<500, 16, true><<<GBLK, 512, 0, stream>>>(x, Wp1, H);
    k_pull128<1><<<NN / 8, 256, 0, stream>>>(H, row_ptr, csr, dinv, b1, nullptr, h1);

    // ---- layer 2: H = h1 @ W2 (MFMA bf16) ; h1 = relu(pull(H) + b2) + h1
    k_gemm_mfma<128, 4, false><<<GBLK, 512, 0, stream>>>(h1, Wp2, H);
    k_pull128<2><<<NN / 8, 256, 0, stream>>>(H, row_ptr, csr, dinv, b2, h1, h1);

    // ---- layer 3: G3 = h1 @ W3 (into H, fp32) ; out = log_softmax(pull(G3) + b3)
    k_gemm40<<<NN / 32, 256, 0, stream>>>(h1, W3, H);
    k_pull40_lsm<<<NN / 4, 256, 0, stream>>>(H, row_ptr, csr, dinv, b3, out);
}

// Round 5
// 641.431 us; speedup vs baseline: 10.9561x; 1.3009x over previous
//
#include <hip/hip_runtime.h>
#include <hip/hip_bf16.h>
#include <type_traits>

#define NN 100000
#define NE 1600000
// IN_CH=500, HID=128, OUT_CH=40

#define SCAN_E 1024
#define NBLK ((NN + SCAN_E - 1) / SCAN_E)  // 98

using f32x4 = __attribute__((ext_vector_type(4))) float;
using bf16x8 = __attribute__((ext_vector_type(8))) short;  // 8 bf16 in 4 VGPRs
using u16 = unsigned short;

__device__ inline u16 f2bf(float f) {
    unsigned u = __float_as_uint(f);
    unsigned r = (u + 0x7fffu + ((u >> 16) & 1u)) >> 16;  // RNE
    return (u16)r;
}
__device__ inline float bflo(unsigned u) { return __uint_as_float(u << 16); }
__device__ inline float bfhi(unsigned u) { return __uint_as_float(u & 0xffff0000u); }
__device__ inline float bf2f(u16 u) { return __uint_as_float((unsigned)u << 16); }
__device__ inline unsigned pack2(float a, float b) {
    return ((unsigned)f2bf(b) << 16) | (unsigned)f2bf(a);
}

// ---------------- graph norm + CSR build ----------------
__global__ __launch_bounds__(256) void k_deg_cnt(const int* __restrict__ ei,
                                                 const float* __restrict__ ea,
                                                 float* __restrict__ deg,
                                                 int* __restrict__ cnt) {
    int e = blockIdx.x * 256 + threadIdx.x;
    if (e < NE) {
        int d = ei[NE + e];
        unsafeAtomicAdd(&deg[d], ea[e]);
        atomicAdd(&cnt[d], 1);
    }
}

__global__ __launch_bounds__(256) void k_dinv(const float* __restrict__ deg,
                                              float* __restrict__ dinv) {
    int i = blockIdx.x * 256 + threadIdx.x;
    if (i < NN) {
        float d = deg[i] + 1.0f;  // + self-loop weight 1
        dinv[i] = rsqrtf(d);
    }
}

__global__ __launch_bounds__(256) void k_scan1(const int* __restrict__ cnt,
                                               int* __restrict__ row_ptr,
                                               int* __restrict__ part) {
    __shared__ int ts[256];
    const int tid = threadIdx.x;
    int base = blockIdx.x * SCAN_E + tid * 4;
    int v[4];
    int ssum = 0;
#pragma unroll
    for (int j = 0; j < 4; j++) {
        v[j] = (base + j < NN) ? cnt[base + j] : 0;
        ssum += v[j];
    }
    ts[tid] = ssum;
    __syncthreads();
    for (int o = 1; o < 256; o <<= 1) {
        int t = (tid >= o) ? ts[tid - o] : 0;
        __syncthreads();
        ts[tid] += t;
        __syncthreads();
    }
    int excl = ts[tid] - ssum;
#pragma unroll
    for (int j = 0; j < 4; j++) {
        if (base + j < NN) row_ptr[base + j] = excl;
        excl += v[j];
    }
    if (tid == 255) part[blockIdx.x] = ts[255];
}

__global__ void k_scan2(int* __restrict__ part) {
    if (threadIdx.x == 0) {
        int acc = 0;
        for (int b = 0; b < NBLK; b++) { int t = part[b]; part[b] = acc; acc += t; }
    }
}

__global__ __launch_bounds__(256) void k_scan3(int* __restrict__ row_ptr,
                                               const int* __restrict__ part,
                                               int* __restrict__ cnt) {
    int base = blockIdx.x * SCAN_E + threadIdx.x * 4;
    int off = part[blockIdx.x];
#pragma unroll
    for (int j = 0; j < 4; j++)
        if (base + j < NN) { row_ptr[base + j] += off; cnt[base + j] = 0; }
    if (blockIdx.x == 0 && threadIdx.x == 0) row_ptr[NN] = NE;
}

__global__ __launch_bounds__(256) void k_scatter(const int* __restrict__ ei,
                                                 const float* __restrict__ ea,
                                                 const float* __restrict__ dinv,
                                                 const int* __restrict__ row_ptr,
                                                 int* __restrict__ cursor,
                                                 int2* __restrict__ csr) {
    int e = blockIdx.x * 256 + threadIdx.x;
    if (e >= NE) return;
    int s = ei[e], d = ei[NE + e];
    int pos = row_ptr[d] + atomicAdd(&cursor[d], 1);
    float w = dinv[s] * ea[e] * dinv[d];
    csr[pos] = make_int2(s, __float_as_int(w));
}

// ---------------- W pack: fragment-ordered bf16 ----------------
__global__ __launch_bounds__(256) void k_packW(const float* __restrict__ W,
                                               short* __restrict__ Wp,
                                               int K, int total) {
    int t = blockIdx.x * 256 + threadIdx.x;
    if (t >= total) return;
    int lane = t & 63;
    int nt = (t >> 6) & 7;
    int ks = t >> 9;
    int col = nt * 16 + (lane & 15);
    int kb = ks * 32 + ((lane >> 4) << 3);
    bf16x8 v;
#pragma unroll
    for (int j = 0; j < 8; j++) {
        int k = kb + j;
        v[j] = (k < K) ? (short)f2bf(W[(size_t)k * 128 + col]) : (short)0;
    }
    reinterpret_cast<bf16x8*>(Wp)[t] = v;
}

// ---------------- MFMA GEMM, N=128, bf16 out ----------------
// A source: fp32 (convert in-register) or bf16 (direct fragment load).
template <typename AT, int KLIM, int KSTEPS, bool TAIL>
__global__ __launch_bounds__(512) void k_gemm_mfma(const AT* __restrict__ X,
                                                   const short* __restrict__ Wp,
                                                   u16* __restrict__ Out) {
    const int lane = threadIdx.x & 63;
    const int wave = threadIdx.x >> 6;
    const int row0 = blockIdx.x * 128 + wave * 16;
    const int arow = row0 + (lane & 15);
    const int kgrp = (lane >> 4) << 3;
    const bool rvalid = arow < NN;
    const AT* aptr = X + (size_t)arow * KLIM + kgrp;
    const bf16x8* wp = reinterpret_cast<const bf16x8*>(Wp);

    f32x4 acc[8];
#pragma unroll
    for (int nt = 0; nt < 8; nt++) acc[nt] = (f32x4){0.f, 0.f, 0.f, 0.f};

    const int FULL = TAIL ? (KSTEPS - 1) : KSTEPS;
#pragma unroll 2
    for (int ks = 0; ks < FULL; ks++) {
        bf16x8 af;
        if (rvalid) {
            if constexpr (std::is_same_v<AT, float>) {
                float4 f0 = *reinterpret_cast<const float4*>(aptr + ks * 32);
                float4 f1 = *reinterpret_cast<const float4*>(aptr + ks * 32 + 4);
                af[0] = (short)f2bf(f0.x); af[1] = (short)f2bf(f0.y);
                af[2] = (short)f2bf(f0.z); af[3] = (short)f2bf(f0.w);
                af[4] = (short)f2bf(f1.x); af[5] = (short)f2bf(f1.y);
                af[6] = (short)f2bf(f1.z); af[7] = (short)f2bf(f1.w);
            } else {
                af = *reinterpret_cast<const bf16x8*>(aptr + ks * 32);
            }
        } else {
#pragma unroll
            for (int j = 0; j < 8; j++) af[j] = 0;
        }
#pragma unroll
        for (int nt = 0; nt < 8; nt++) {
            bf16x8 bf = wp[(ks * 8 + nt) * 64 + lane];
            acc[nt] = __builtin_amdgcn_mfma_f32_16x16x32_bf16(af, bf, acc[nt], 0, 0, 0);
        }
    }
    if (TAIL) {
        const int ks = KSTEPS - 1;
        bf16x8 af;
#pragma unroll
        for (int j = 0; j < 8; j++) {
            int k = ks * 32 + kgrp + j;
            bool ok = rvalid && k < KLIM;
            if constexpr (std::is_same_v<AT, float>) {
                af[j] = (short)f2bf(ok ? aptr[ks * 32 + j] : 0.f);
            } else {
                af[j] = ok ? (short)aptr[ks * 32 + j] : (short)0;
            }
        }
#pragma unroll
        for (int nt = 0; nt < 8; nt++) {
            bf16x8 bf = wp[(ks * 8 + nt) * 64 + lane];
            acc[nt] = __builtin_amdgcn_mfma_f32_16x16x32_bf16(af, bf, acc[nt], 0, 0, 0);
        }
    }

    const int rbase = row0 + ((lane >> 4) << 2);
    const int cbase = lane & 15;
#pragma unroll
    for (int r = 0; r < 4; r++) {
        int orow = rbase + r;
        if (orow < NN) {
            u16* orow_p = Out + (size_t)orow * 128 + cbase;
#pragma unroll
            for (int nt = 0; nt < 8; nt++) orow_p[nt * 16] = f2bf(acc[nt][r]);
        }
    }
}

// ---------------- GEMM, K=128 (bf16 A), N=40, bf16 out ----------------
__global__ __launch_bounds__(256) void k_gemm40(const u16* __restrict__ Xb,
                                                const float* __restrict__ W,
                                                u16* __restrict__ Out) {
    __shared__ float xs[128][32];
    const int tid = threadIdx.x;
    const int col = tid & 63;
    const int rbase = (tid >> 6) * 8;
    const int row0 = blockIdx.x * 32;

    for (int idx = tid; idx < 1024; idx += 256) {
        int r = idx & 31;
        int k4 = idx >> 5;  // 0..31, 4 channels each
        uint2 v = *reinterpret_cast<const uint2*>(Xb + (size_t)(row0 + r) * 128 + k4 * 4);
        xs[k4 * 4 + 0][r] = bflo(v.x);
        xs[k4 * 4 + 1][r] = bfhi(v.x);
        xs[k4 * 4 + 2][r] = bflo(v.y);
        xs[k4 * 4 + 3][r] = bfhi(v.y);
    }
    __syncthreads();

    float acc[8];
#pragma unroll
    for (int i = 0; i < 8; i++) acc[i] = 0.f;

#pragma unroll 2
    for (int k = 0; k < 128; k++) {
        float w = (col < 40) ? W[k * 40 + col] : 0.f;
        const float* xr = &xs[k][rbase];
#pragma unroll
        for (int i = 0; i < 8; i++) acc[i] = fmaf(xr[i], w, acc[i]);
    }
    if (col < 40) {
#pragma unroll
        for (int i = 0; i < 8; i++)
            Out[(size_t)(row0 + rbase + i) * 40 + col] = f2bf(acc[i]);
    }
}

// ---------------- CSR pull aggregation, 128 ch bf16 ----------------
// 32 lanes/node (uint2 = 4 bf16 each), 8 nodes/block. Cooperative header
// loads + shfl broadcast + 4-way unrolled gathers; fp32 accumulate.
// MODE 1: out = relu(acc+b)    MODE 2: out = relu(acc+b) + R[node] (bf16)
template <int MODE>
__global__ __launch_bounds__(256) void k_pull128(const u16* __restrict__ H,
                                                 const int* __restrict__ row_ptr,
                                                 const int2* __restrict__ csr,
                                                 const float* __restrict__ dinv,
                                                 const float* __restrict__ b,
                                                 const u16* __restrict__ R,
                                                 u16* __restrict__ Out) {
    int node = blockIdx.x * 8 + (threadIdx.x >> 5);
    int cg = threadIdx.x & 31;
    const uint2* H2 = reinterpret_cast<const uint2*>(H);  // row stride 32
    float dv = dinv[node];
    float sw = dv * dv;  // self-loop weight
    uint2 h = H2[node * 32 + cg];
    float4 acc;
    acc.x = bflo(h.x) * sw; acc.y = bfhi(h.x) * sw;
    acc.z = bflo(h.y) * sw; acc.w = bfhi(h.y) * sw;

    int e0 = row_ptr[node], e1 = row_ptr[node + 1];
    for (int base = e0; base < e1; base += 32) {
        int n = e1 - base;
        if (n > 32) n = 32;
        int2 sv = (cg < n) ? csr[base + cg] : make_int2(0, 0);
        int j = 0;
        for (; j + 4 <= n; j += 4) {
            int s0 = __shfl(sv.x, j + 0, 32);
            int s1 = __shfl(sv.x, j + 1, 32);
            int s2 = __shfl(sv.x, j + 2, 32);
            int s3 = __shfl(sv.x, j + 3, 32);
            float w0 = __int_as_float(__shfl(sv.y, j + 0, 32));
            float w1 = __int_as_float(__shfl(sv.y, j + 1, 32));
            float w2 = __int_as_float(__shfl(sv.y, j + 2, 32));
            float w3 = __int_as_float(__shfl(sv.y, j + 3, 32));
            uint2 g0 = H2[s0 * 32 + cg];
            uint2 g1 = H2[s1 * 32 + cg];
            uint2 g2 = H2[s2 * 32 + cg];
            uint2 g3 = H2[s3 * 32 + cg];
            acc.x = fmaf(w0, bflo(g0.x), acc.x); acc.y = fmaf(w0, bfhi(g0.x), acc.y);
            acc.z = fmaf(w0, bflo(g0.y), acc.z); acc.w = fmaf(w0, bfhi(g0.y), acc.w);
            acc.x = fmaf(w1, bflo(g1.x), acc.x); acc.y = fmaf(w1, bfhi(g1.x), acc.y);
            acc.z = fmaf(w1, bflo(g1.y), acc.z); acc.w = fmaf(w1, bfhi(g1.y), acc.w);
            acc.x = fmaf(w2, bflo(g2.x), acc.x); acc.y = fmaf(w2, bfhi(g2.x), acc.y);
            acc.z = fmaf(w2, bflo(g2.y), acc.z); acc.w = fmaf(w2, bfhi(g2.y), acc.w);
            acc.x = fmaf(w3, bflo(g3.x), acc.x); acc.y = fmaf(w3, bfhi(g3.x), acc.y);
            acc.z = fmaf(w3, bflo(g3.y), acc.z); acc.w = fmaf(w3, bfhi(g3.y), acc.w);
        }
        for (; j < n; j++) {
            int s = __shfl(sv.x, j, 32);
            float w = __int_as_float(__shfl(sv.y, j, 32));
            uint2 g = H2[s * 32 + cg];
            acc.x = fmaf(w, bflo(g.x), acc.x); acc.y = fmaf(w, bfhi(g.x), acc.y);
            acc.z = fmaf(w, bflo(g.y), acc.z); acc.w = fmaf(w, bfhi(g.y), acc.w);
        }
    }

    float4 bb = reinterpret_cast<const float4*>(b)[cg];
    float4 o;
    o.x = fmaxf(acc.x + bb.x, 0.f);
    o.y = fmaxf(acc.y + bb.y, 0.f);
    o.z = fmaxf(acc.z + bb.z, 0.f);
    o.w = fmaxf(acc.w + bb.w, 0.f);
    if (MODE == 2) {
        uint2 r = reinterpret_cast<const uint2*>(R)[node * 32 + cg];
        o.x += bflo(r.x); o.y += bfhi(r.x);
        o.z += bflo(r.y); o.w += bfhi(r.y);
    }
    reinterpret_cast<uint2*>(Out)[node * 32 + cg] =
        make_uint2(pack2(o.x, o.y), pack2(o.z, o.w));
}

// ---------------- layer 3: pull(40ch bf16) + bias + log_softmax ----------------
__global__ __launch_bounds__(256) void k_pull40_lsm(const u16* __restrict__ G,
                                                    const int* __restrict__ row_ptr,
                                                    const int2* __restrict__ csr,
                                                    const float* __restrict__ dinv,
                                                    const float* __restrict__ b3,
                                                    float* __restrict__ out) {
    int node = blockIdx.x * 4 + (threadIdx.x >> 6);
    int lane = threadIdx.x & 63;
    const bool act = lane < 40;
    float dv = dinv[node];
    float sw = dv * dv;
    float acc = act ? bf2f(G[node * 40 + lane]) * sw : 0.f;

    int e0 = row_ptr[node], e1 = row_ptr[node + 1];
    for (int base = e0; base < e1; base += 64) {
        int n = e1 - base;
        if (n > 64) n = 64;
        int2 sv = (lane < n) ? csr[base + lane] : make_int2(0, 0);
        int j = 0;
        for (; j + 4 <= n; j += 4) {
            int s0 = __shfl(sv.x, j + 0);
            int s1 = __shfl(sv.x, j + 1);
            int s2 = __shfl(sv.x, j + 2);
            int s3 = __shfl(sv.x, j + 3);
            float w0 = __int_as_float(__shfl(sv.y, j + 0));
            float w1 = __int_as_float(__shfl(sv.y, j + 1));
            float w2 = __int_as_float(__shfl(sv.y, j + 2));
            float w3 = __int_as_float(__shfl(sv.y, j + 3));
            float g0 = act ? bf2f(G[s0 * 40 + lane]) : 0.f;
            float g1 = act ? bf2f(G[s1 * 40 + lane]) : 0.f;
            float g2 = act ? bf2f(G[s2 * 40 + lane]) : 0.f;
            float g3 = act ? bf2f(G[s3 * 40 + lane]) : 0.f;
            acc = fmaf(w0, g0, acc);
            acc = fmaf(w1, g1, acc);
            acc = fmaf(w2, g2, acc);
            acc = fmaf(w3, g3, acc);
        }
        for (; j < n; j++) {
            int s = __shfl(sv.x, j);
            float w = __int_as_float(__shfl(sv.y, j));
            float g = act ? bf2f(G[s * 40 + lane]) : 0.f;
            acc = fmaf(w, g, acc);
        }
    }

    float v = act ? acc + b3[lane] : -1e30f;
    float m = v;
    for (int o = 32; o; o >>= 1) m = fmaxf(m, __shfl_xor(m, o));
    float e = act ? expf(v - m) : 0.f;
    float ssum = e;
    for (int o = 32; o; o >>= 1) ssum += __shfl_xor(ssum, o);
    float ls = logf(ssum);
    if (act) out[node * 40 + lane] = v - m - ls;
}

// ---------------- launch ----------------
extern "C" void kernel_launch(void* const* d_in, const int* in_sizes, int n_in,
                              void* d_out, int out_size, void* d_ws, size_t ws_size,
                              hipStream_t stream) {
    const float* x  = (const float*)d_in[0];
    const int*   ei = (const int*)d_in[1];   // [2, NE] int32
    const float* ea = (const float*)d_in[2];
    const float* W1 = (const float*)d_in[3];
    const float* b1 = (const float*)d_in[4];
    const float* W2 = (const float*)d_in[5];
    const float* b2 = (const float*)d_in[6];
    const float* W3 = (const float*)d_in[7];
    const float* b3 = (const float*)d_in[8];
    float* out = (float*)d_out;

    // workspace carve-up (all regions 16 B aligned)
    short* Wp1     = (short*)d_ws;                   // 65536 bf16 (128 KB)
    short* Wp2     = Wp1 + 65536;                    // 16384 bf16 (32 KB)
    u16*   Hb      = (u16*)(Wp2 + 16384);            // NN*128 bf16 (GEMM1/2 out, gather src)
    u16*   h1b     = Hb + (size_t)NN * 128;          // NN*128 bf16 (h1 / h2 in-place)
    u16*   G3b     = h1b + (size_t)NN * 128;         // NN*40 bf16
    float* deg     = (float*)(G3b + (size_t)NN * 40);// NN f32
    int*   cnt     = (int*)(deg + NN);               // NN i32 (then scatter cursor)
    float* dinv    = (float*)(cnt + NN);             // NN f32
    int*   row_ptr = (int*)(dinv + NN);              // NN+1 (pad 8)
    int*   part    = row_ptr + NN + 8;               // NBLK (pad 128)
    int2*  csr     = (int2*)(part + 128);            // NE int2

    // ---- CSR build + norm + W packing
    hipMemsetAsync(deg, 0, NN * 8, stream);  // zeroes deg AND cnt (adjacent)
    k_deg_cnt<<<(NE + 255) / 256, 256, 0, stream>>>(ei, ea, deg, cnt);
    k_dinv<<<(NN + 255) / 256, 256, 0, stream>>>(deg, dinv);
    k_scan1<<<NBLK, 256, 0, stream>>>(cnt, row_ptr, part);
    k_scan2<<<1, 64, 0, stream>>>(part);
    k_scan3<<<NBLK, 256, 0, stream>>>(row_ptr, part, cnt);  // also zeroes cnt
    k_scatter<<<(NE + 255) / 256, 256, 0, stream>>>(ei, ea, dinv, row_ptr, cnt, csr);
    k_packW<<<32, 256, 0, stream>>>(W1, Wp1, 500, 16 * 8 * 64);
    k_packW<<<8, 256, 0, stream>>>(W2, Wp2, 128, 4 * 8 * 64);

    const int GBLK = (NN + 127) / 128;  // 782

    // ---- layer 1: Hb = X @ W1 (bf16) ; h1b = relu(pull(Hb) + b1) (bf16)
    k_gemm_mfma<float, 500, 16, true><<<GBLK, 512, 0, stream>>>(x, Wp1, Hb);
    k_pull128<1><<<NN / 8, 256, 0, stream>>>(Hb, row_ptr, csr, dinv, b1, nullptr, h1b);

    // ---- layer 2: Hb = h1b @ W2 (bf16 A) ; h1b = relu(pull(Hb)+b2) + h1b (in-place)
    k_gemm_mfma<u16, 128, 4, false><<<GBLK, 512, 0, stream>>>(h1b, Wp2, Hb);
    k_pull128<2><<<NN / 8, 256, 0, stream>>>(Hb, row_ptr, csr, dinv, b2, h1b, h1b);

    // ---- layer 3: G3b = h2 @ W3 (bf16) ; out = log_softmax(pull(G3b) + b3)
    k_gemm40<<<NN / 32, 256, 0, stream>>>(h1b, W3, G3b);
    k_pull40_lsm<<<NN / 4, 256, 0, stream>>>(G3b, row_ptr, csr, dinv, b3, out);
}

// Round 6
// 514.514 us; speedup vs baseline: 13.6587x; 1.2467x over previous
//
#include <hip/hip_runtime.h>
#include <hip/hip_bf16.h>
#include <type_traits>

#define NN 100000
#define NE 1600000
// IN_CH=500, HID=128, OUT_CH=40

#define SCAN_E 1024
#define NBLK ((NN + SCAN_E - 1) / SCAN_E)  // 98
#define GBLK ((NN + 127) / 128)            // 782 gemm blocks (128 rows each)
#define EBLK ((NE + 511) / 512)            // 3125 edge blocks in fused kernel

using f32x4 = __attribute__((ext_vector_type(4))) float;
using bf16x8 = __attribute__((ext_vector_type(8))) short;  // 8 bf16 in 4 VGPRs
using u16 = unsigned short;
using u64 = unsigned long long;

__device__ inline u16 f2bf(float f) {
    unsigned u = __float_as_uint(f);
    unsigned r = (u + 0x7fffu + ((u >> 16) & 1u)) >> 16;  // RNE
    return (u16)r;
}
__device__ inline float bflo(unsigned u) { return __uint_as_float(u << 16); }
__device__ inline float bfhi(unsigned u) { return __uint_as_float(u & 0xffff0000u); }
__device__ inline float bf2f(u16 u) { return __uint_as_float((unsigned)u << 16); }
// packed fp32x2 -> bf16x2 (RNE); compiler lowers to v_cvt_pk_bf16_f32 on gfx950
__device__ inline unsigned cvt2(float a, float b) {
    union { __hip_bfloat162 h; unsigned u; } c;
    c.h = __float22bfloat162_rn(make_float2(a, b));
    return c.u;
}

// ---------------- MFMA GEMM body, N=128, bf16 out ----------------
template <typename AT, int KLIM, int KSTEPS, bool TAIL>
__device__ __forceinline__ void gemm_body(const AT* __restrict__ X,
                                          const short* __restrict__ Wp,
                                          u16* __restrict__ Out) {
    const int lane = threadIdx.x & 63;
    const int wave = threadIdx.x >> 6;
    const int row0 = blockIdx.x * 128 + wave * 16;
    const int arow = row0 + (lane & 15);
    const int kgrp = (lane >> 4) << 3;
    const bool rvalid = arow < NN;
    const AT* aptr = X + (size_t)arow * KLIM + kgrp;
    const bf16x8* wp = reinterpret_cast<const bf16x8*>(Wp);

    f32x4 acc[8];
#pragma unroll
    for (int nt = 0; nt < 8; nt++) acc[nt] = (f32x4){0.f, 0.f, 0.f, 0.f};

    const int FULL = TAIL ? (KSTEPS - 1) : KSTEPS;
#pragma unroll 2
    for (int ks = 0; ks < FULL; ks++) {
        bf16x8 af;
        if (rvalid) {
            if constexpr (std::is_same_v<AT, float>) {
                float4 f0 = *reinterpret_cast<const float4*>(aptr + ks * 32);
                float4 f1 = *reinterpret_cast<const float4*>(aptr + ks * 32 + 4);
                union { bf16x8 v; unsigned u[4]; } a;
                a.u[0] = cvt2(f0.x, f0.y);
                a.u[1] = cvt2(f0.z, f0.w);
                a.u[2] = cvt2(f1.x, f1.y);
                a.u[3] = cvt2(f1.z, f1.w);
                af = a.v;
            } else {
                af = *reinterpret_cast<const bf16x8*>(aptr + ks * 32);
            }
        } else {
#pragma unroll
            for (int j = 0; j < 8; j++) af[j] = 0;
        }
#pragma unroll
        for (int nt = 0; nt < 8; nt++) {
            bf16x8 bf = wp[(ks * 8 + nt) * 64 + lane];
            acc[nt] = __builtin_amdgcn_mfma_f32_16x16x32_bf16(af, bf, acc[nt], 0, 0, 0);
        }
    }
    if (TAIL) {
        const int ks = KSTEPS - 1;
        bf16x8 af;
#pragma unroll
        for (int j = 0; j < 8; j++) {
            int k = ks * 32 + kgrp + j;
            bool ok = rvalid && k < KLIM;
            if constexpr (std::is_same_v<AT, float>) {
                af[j] = (short)f2bf(ok ? aptr[ks * 32 + j] : 0.f);
            } else {
                af[j] = ok ? (short)aptr[ks * 32 + j] : (short)0;
            }
        }
#pragma unroll
        for (int nt = 0; nt < 8; nt++) {
            bf16x8 bf = wp[(ks * 8 + nt) * 64 + lane];
            acc[nt] = __builtin_amdgcn_mfma_f32_16x16x32_bf16(af, bf, acc[nt], 0, 0, 0);
        }
    }

    const int rbase = row0 + ((lane >> 4) << 2);
    const int cbase = lane & 15;
#pragma unroll
    for (int r = 0; r < 4; r++) {
        int orow = rbase + r;
        if (orow < NN) {
            u16* p = Out + (size_t)orow * 128 + cbase;
#pragma unroll
            for (int nt = 0; nt < 8; nt += 2) {
                unsigned v = cvt2(acc[nt][r], acc[nt + 1][r]);
                p[nt * 16] = (u16)v;
                p[nt * 16 + 16] = (u16)(v >> 16);
            }
        }
    }
}

// ---------------- fused: GEMM1 (blocks < GBLK)  +  degree/count pass (rest) ----------------
// dc[d] 64-bit: high = edge count, low = sum(ea) in 2^-24 fixed point.
// Returned old high word = this edge's within-node rank (used by atomic-free scatter).
__global__ __launch_bounds__(512) void k_gemm1_deg(const float* __restrict__ X,
                                                   const short* __restrict__ Wp,
                                                   u16* __restrict__ Out,
                                                   const int* __restrict__ ei,
                                                   const float* __restrict__ ea,
                                                   u64* __restrict__ dc,
                                                   int* __restrict__ rank) {
    if (blockIdx.x >= GBLK) {
        int e = (blockIdx.x - GBLK) * 512 + threadIdx.x;
        if (e < NE) {
            int d = ei[NE + e];
            u64 add = (1ULL << 32) | (u64)(unsigned)(ea[e] * 16777216.0f);
            u64 old = atomicAdd(dc + d, add);
            rank[e] = (int)(old >> 32);
        }
        return;
    }
    gemm_body<float, 500, 16, true>(X, Wp, Out);
}

// ---------------- standalone MFMA GEMM (layer 2) ----------------
template <typename AT, int KLIM, int KSTEPS, bool TAIL>
__global__ __launch_bounds__(512) void k_gemm_mfma(const AT* __restrict__ X,
                                                   const short* __restrict__ Wp,
                                                   u16* __restrict__ Out) {
    gemm_body<AT, KLIM, KSTEPS, TAIL>(X, Wp, Out);
}

// ---------------- graph norm ----------------
__global__ __launch_bounds__(256) void k_dinv(const u64* __restrict__ dc,
                                              float* __restrict__ dinv) {
    int i = blockIdx.x * 256 + threadIdx.x;
    if (i < NN) {
        uint2 v = reinterpret_cast<const uint2*>(dc)[i];
        float d = (float)v.x * (1.0f / 16777216.0f) + 1.0f;  // + self-loop weight 1
        dinv[i] = rsqrtf(d);
    }
}

// block-local exclusive scan of counts (1024 elems/block), block sums -> part
__global__ __launch_bounds__(256) void k_scan1(const u64* __restrict__ dc,
                                               int* __restrict__ row_ptr,
                                               int* __restrict__ part) {
    __shared__ int ts[256];
    const int tid = threadIdx.x;
    int base = blockIdx.x * SCAN_E + tid * 4;
    int v[4];
    int ssum = 0;
#pragma unroll
    for (int j = 0; j < 4; j++) {
        v[j] = (base + j < NN) ? (int)(dc[base + j] >> 32) : 0;
        ssum += v[j];
    }
    ts[tid] = ssum;
    __syncthreads();
    for (int o = 1; o < 256; o <<= 1) {
        int t = (tid >= o) ? ts[tid - o] : 0;
        __syncthreads();
        ts[tid] += t;
        __syncthreads();
    }
    int excl = ts[tid] - ssum;
#pragma unroll
    for (int j = 0; j < 4; j++) {
        if (base + j < NN) row_ptr[base + j] = excl;
        excl += v[j];
    }
    if (tid == 255) part[blockIdx.x] = ts[255];
}

__global__ void k_scan2(int* __restrict__ part) {
    if (threadIdx.x == 0) {
        int acc = 0;
        for (int b = 0; b < NBLK; b++) { int t = part[b]; part[b] = acc; acc += t; }
    }
}

__global__ __launch_bounds__(256) void k_scan3(int* __restrict__ row_ptr,
                                               const int* __restrict__ part) {
    int base = blockIdx.x * SCAN_E + threadIdx.x * 4;
    int off = part[blockIdx.x];
#pragma unroll
    for (int j = 0; j < 4; j++)
        if (base + j < NN) row_ptr[base + j] += off;
    if (blockIdx.x == 0 && threadIdx.x == 0) row_ptr[NN] = NE;
}

// atomic-free scatter: slot = row_ptr[dst] + rank[e]
__global__ __launch_bounds__(256) void k_scatter(const int* __restrict__ ei,
                                                 const float* __restrict__ ea,
                                                 const float* __restrict__ dinv,
                                                 const int* __restrict__ row_ptr,
                                                 const int* __restrict__ rank,
                                                 int2* __restrict__ csr) {
    int e = blockIdx.x * 256 + threadIdx.x;
    if (e >= NE) return;
    int s = ei[e], d = ei[NE + e];
    int pos = row_ptr[d] + rank[e];
    float w = dinv[s] * ea[e] * dinv[d];
    csr[pos] = make_int2(s, __float_as_int(w));
}

// ---------------- W pack: fragment-ordered bf16 ----------------
__global__ __launch_bounds__(256) void k_packW(const float* __restrict__ W,
                                               short* __restrict__ Wp,
                                               int K, int total) {
    int t = blockIdx.x * 256 + threadIdx.x;
    if (t >= total) return;
    int lane = t & 63;
    int nt = (t >> 6) & 7;
    int ks = t >> 9;
    int col = nt * 16 + (lane & 15);
    int kb = ks * 32 + ((lane >> 4) << 3);
    bf16x8 v;
#pragma unroll
    for (int j = 0; j < 8; j++) {
        int k = kb + j;
        v[j] = (k < K) ? (short)f2bf(W[(size_t)k * 128 + col]) : (short)0;
    }
    reinterpret_cast<bf16x8*>(Wp)[t] = v;
}

// ---------------- GEMM, K=128 (bf16 A), N=40, bf16 out ----------------
__global__ __launch_bounds__(256) void k_gemm40(const u16* __restrict__ Xb,
                                                const float* __restrict__ W,
                                                u16* __restrict__ Out) {
    __shared__ float xs[128][32];
    const int tid = threadIdx.x;
    const int col = tid & 63;
    const int rbase = (tid >> 6) * 8;
    const int row0 = blockIdx.x * 32;

    for (int idx = tid; idx < 1024; idx += 256) {
        int r = idx & 31;
        int k4 = idx >> 5;  // 0..31, 4 channels each
        uint2 v = *reinterpret_cast<const uint2*>(Xb + (size_t)(row0 + r) * 128 + k4 * 4);
        xs[k4 * 4 + 0][r] = bflo(v.x);
        xs[k4 * 4 + 1][r] = bfhi(v.x);
        xs[k4 * 4 + 2][r] = bflo(v.y);
        xs[k4 * 4 + 3][r] = bfhi(v.y);
    }
    __syncthreads();

    float acc[8];
#pragma unroll
    for (int i = 0; i < 8; i++) acc[i] = 0.f;

#pragma unroll 2
    for (int k = 0; k < 128; k++) {
        float w = (col < 40) ? W[k * 40 + col] : 0.f;
        const float* xr = &xs[k][rbase];
#pragma unroll
        for (int i = 0; i < 8; i++) acc[i] = fmaf(xr[i], w, acc[i]);
    }
    if (col < 40) {
#pragma unroll
        for (int i = 0; i < 8; i++)
            Out[(size_t)(row0 + rbase + i) * 40 + col] = f2bf(acc[i]);
    }
}

// ---------------- CSR pull aggregation, 128 ch bf16 ----------------
// 32 lanes/node (uint2 = 4 bf16 each), 8 nodes/block. Cooperative header
// loads + shfl broadcast + 4-way unrolled gathers; fp32 accumulate.
// MODE 1: out = relu(acc+b)    MODE 2: out = relu(acc+b) + R[node] (bf16)
template <int MODE>
__global__ __launch_bounds__(256) void k_pull128(const u16* __restrict__ H,
                                                 const int* __restrict__ row_ptr,
                                                 const int2* __restrict__ csr,
                                                 const float* __restrict__ dinv,
                                                 const float* __restrict__ b,
                                                 const u16* __restrict__ R,
                                                 u16* __restrict__ Out) {
    int node = blockIdx.x * 8 + (threadIdx.x >> 5);
    int cg = threadIdx.x & 31;
    const uint2* H2 = reinterpret_cast<const uint2*>(H);  // row stride 32
    float dv = dinv[node];
    float sw = dv * dv;  // self-loop weight
    uint2 h = H2[node * 32 + cg];
    float4 acc;
    acc.x = bflo(h.x) * sw; acc.y = bfhi(h.x) * sw;
    acc.z = bflo(h.y) * sw; acc.w = bfhi(h.y) * sw;

    int e0 = row_ptr[node], e1 = row_ptr[node + 1];
    for (int base = e0; base < e1; base += 32) {
        int n = e1 - base;
        if (n > 32) n = 32;
        int2 sv = (cg < n) ? csr[base + cg] : make_int2(0, 0);
        int j = 0;
        for (; j + 4 <= n; j += 4) {
            int s0 = __shfl(sv.x, j + 0, 32);
            int s1 = __shfl(sv.x, j + 1, 32);
            int s2 = __shfl(sv.x, j + 2, 32);
            int s3 = __shfl(sv.x, j + 3, 32);
            float w0 = __int_as_float(__shfl(sv.y, j + 0, 32));
            float w1 = __int_as_float(__shfl(sv.y, j + 1, 32));
            float w2 = __int_as_float(__shfl(sv.y, j + 2, 32));
            float w3 = __int_as_float(__shfl(sv.y, j + 3, 32));
            uint2 g0 = H2[s0 * 32 + cg];
            uint2 g1 = H2[s1 * 32 + cg];
            uint2 g2 = H2[s2 * 32 + cg];
            uint2 g3 = H2[s3 * 32 + cg];
            acc.x = fmaf(w0, bflo(g0.x), acc.x); acc.y = fmaf(w0, bfhi(g0.x), acc.y);
            acc.z = fmaf(w0, bflo(g0.y), acc.z); acc.w = fmaf(w0, bfhi(g0.y), acc.w);
            acc.x = fmaf(w1, bflo(g1.x), acc.x); acc.y = fmaf(w1, bfhi(g1.x), acc.y);
            acc.z = fmaf(w1, bflo(g1.y), acc.z); acc.w = fmaf(w1, bfhi(g1.y), acc.w);
            acc.x = fmaf(w2, bflo(g2.x), acc.x); acc.y = fmaf(w2, bfhi(g2.x), acc.y);
            acc.z = fmaf(w2, bflo(g2.y), acc.z); acc.w = fmaf(w2, bfhi(g2.y), acc.w);
            acc.x = fmaf(w3, bflo(g3.x), acc.x); acc.y = fmaf(w3, bfhi(g3.x), acc.y);
            acc.z = fmaf(w3, bflo(g3.y), acc.z); acc.w = fmaf(w3, bfhi(g3.y), acc.w);
        }
        for (; j < n; j++) {
            int s = __shfl(sv.x, j, 32);
            float w = __int_as_float(__shfl(sv.y, j, 32));
            uint2 g = H2[s * 32 + cg];
            acc.x = fmaf(w, bflo(g.x), acc.x); acc.y = fmaf(w, bfhi(g.x), acc.y);
            acc.z = fmaf(w, bflo(g.y), acc.z); acc.w = fmaf(w, bfhi(g.y), acc.w);
        }
    }

    float4 bb = reinterpret_cast<const float4*>(b)[cg];
    float4 o;
    o.x = fmaxf(acc.x + bb.x, 0.f);
    o.y = fmaxf(acc.y + bb.y, 0.f);
    o.z = fmaxf(acc.z + bb.z, 0.f);
    o.w = fmaxf(acc.w + bb.w, 0.f);
    if (MODE == 2) {
        uint2 r = reinterpret_cast<const uint2*>(R)[node * 32 + cg];
        o.x += bflo(r.x); o.y += bfhi(r.x);
        o.z += bflo(r.y); o.w += bfhi(r.y);
    }
    reinterpret_cast<uint2*>(Out)[node * 32 + cg] =
        make_uint2(cvt2(o.x, o.y), cvt2(o.z, o.w));
}

// ---------------- layer 3: pull(40ch bf16) + bias + log_softmax ----------------
__global__ __launch_bounds__(256) void k_pull40_lsm(const u16* __restrict__ G,
                                                    const int* __restrict__ row_ptr,
                                                    const int2* __restrict__ csr,
                                                    const float* __restrict__ dinv,
                                                    const float* __restrict__ b3,
                                                    float* __restrict__ out) {
    int node = blockIdx.x * 4 + (threadIdx.x >> 6);
    int lane = threadIdx.x & 63;
    const bool act = lane < 40;
    float dv = dinv[node];
    float sw = dv * dv;
    float acc = act ? bf2f(G[node * 40 + lane]) * sw : 0.f;

    int e0 = row_ptr[node], e1 = row_ptr[node + 1];
    for (int base = e0; base < e1; base += 64) {
        int n = e1 - base;
        if (n > 64) n = 64;
        int2 sv = (lane < n) ? csr[base + lane] : make_int2(0, 0);
        int j = 0;
        for (; j + 4 <= n; j += 4) {
            int s0 = __shfl(sv.x, j + 0);
            int s1 = __shfl(sv.x, j + 1);
            int s2 = __shfl(sv.x, j + 2);
            int s3 = __shfl(sv.x, j + 3);
            float w0 = __int_as_float(__shfl(sv.y, j + 0));
            float w1 = __int_as_float(__shfl(sv.y, j + 1));
            float w2 = __int_as_float(__shfl(sv.y, j + 2));
            float w3 = __int_as_float(__shfl(sv.y, j + 3));
            float g0 = act ? bf2f(G[s0 * 40 + lane]) : 0.f;
            float g1 = act ? bf2f(G[s1 * 40 + lane]) : 0.f;
            float g2 = act ? bf2f(G[s2 * 40 + lane]) : 0.f;
            float g3 = act ? bf2f(G[s3 * 40 + lane]) : 0.f;
            acc = fmaf(w0, g0, acc);
            acc = fmaf(w1, g1, acc);
            acc = fmaf(w2, g2, acc);
            acc = fmaf(w3, g3, acc);
        }
        for (; j < n; j++) {
            int s = __shfl(sv.x, j);
            float w = __int_as_float(__shfl(sv.y, j));
            float g = act ? bf2f(G[s * 40 + lane]) : 0.f;
            acc = fmaf(w, g, acc);
        }
    }

    float v = act ? acc + b3[lane] : -1e30f;
    float m = v;
    for (int o = 32; o; o >>= 1) m = fmaxf(m, __shfl_xor(m, o));
    float e = act ? expf(v - m) : 0.f;
    float ssum = e;
    for (int o = 32; o; o >>= 1) ssum += __shfl_xor(ssum, o);
    float ls = logf(ssum);
    if (act) out[node * 40 + lane] = v - m - ls;
}

// ---------------- launch ----------------
extern "C" void kernel_launch(void* const* d_in, const int* in_sizes, int n_in,
                              void* d_out, int out_size, void* d_ws, size_t ws_size,
                              hipStream_t stream) {
    const float* x  = (const float*)d_in[0];
    const int*   ei = (const int*)d_in[1];   // [2, NE] int32
    const float* ea = (const float*)d_in[2];
    const float* W1 = (const float*)d_in[3];
    const float* b1 = (const float*)d_in[4];
    const float* W2 = (const float*)d_in[5];
    const float* b2 = (const float*)d_in[6];
    const float* W3 = (const float*)d_in[7];
    const float* b3 = (const float*)d_in[8];
    float* out = (float*)d_out;

    // workspace carve-up (all regions 16 B aligned)
    short* Wp1     = (short*)d_ws;                    // 65536 bf16 (128 KB)
    short* Wp2     = Wp1 + 65536;                     // 16384 bf16 (32 KB)
    u16*   Hb      = (u16*)(Wp2 + 16384);             // NN*128 bf16
    u16*   h1b     = Hb + (size_t)NN * 128;           // NN*128 bf16
    u16*   G3b     = h1b + (size_t)NN * 128;          // NN*40 bf16
    u64*   dc      = (u64*)(G3b + (size_t)NN * 40);   // NN u64 (count|fx-sum)
    float* dinv    = (float*)(dc + NN);               // NN f32
    int*   row_ptr = (int*)(dinv + NN);               // NN+1 (pad 8)
    int*   part    = row_ptr + NN + 8;                // NBLK (pad 128)
    int*   rank    = part + 128;                      // NE i32
    int2*  csr     = (int2*)(rank + NE);              // NE int2

    // ---- W packing + zero dc
    hipMemsetAsync(dc, 0, NN * sizeof(u64), stream);
    k_packW<<<32, 256, 0, stream>>>(W1, Wp1, 500, 16 * 8 * 64);
    k_packW<<<8, 256, 0, stream>>>(W2, Wp2, 128, 4 * 8 * 64);

    // ---- fused: Hb = X @ W1 (bf16 MFMA)  ||  degree/count atomics + rank
    k_gemm1_deg<<<GBLK + EBLK, 512, 0, stream>>>(x, Wp1, Hb, ei, ea, dc, rank);

    // ---- CSR finalize
    k_dinv<<<(NN + 255) / 256, 256, 0, stream>>>(dc, dinv);
    k_scan1<<<NBLK, 256, 0, stream>>>(dc, row_ptr, part);
    k_scan2<<<1, 64, 0, stream>>>(part);
    k_scan3<<<NBLK, 256, 0, stream>>>(row_ptr, part);
    k_scatter<<<(NE + 255) / 256, 256, 0, stream>>>(ei, ea, dinv, row_ptr, rank, csr);

    // ---- layer 1 aggregation: h1b = relu(pull(Hb) + b1)
    k_pull128<1><<<NN / 8, 256, 0, stream>>>(Hb, row_ptr, csr, dinv, b1, nullptr, h1b);

    // ---- layer 2: Hb = h1b @ W2 ; h1b = relu(pull(Hb)+b2) + h1b (in-place)
    k_gemm_mfma<u16, 128, 4, false><<<GBLK, 512, 0, stream>>>(h1b, Wp2, Hb);
    k_pull128<2><<<NN / 8, 256, 0, stream>>>(Hb, row_ptr, csr, dinv, b2, h1b, h1b);

    // ---- layer 3: G3b = h2 @ W3 ; out = log_softmax(pull(G3b) + b3)
    k_gemm40<<<NN / 32, 256, 0, stream>>>(h1b, W3, G3b);
    k_pull40_lsm<<<NN / 4, 256, 0, stream>>>(G3b, row_ptr, csr, dinv, b3, out);
}